// Round 12
// baseline (817.825 us; speedup 1.0000x reference)
//
#include <hip/hip_runtime.h>
#include <cmath>

#define NPIX 1024
#define NEDGE 1984
#define NPAD 2048
#define KTOP 256
#define NITER 150

typedef __attribute__((ext_vector_type(8))) short bf16x8_t;   // 8 bf16 = 4 VGPRs
typedef __attribute__((ext_vector_type(4))) float f32x4_t;

__device__ __forceinline__ unsigned bf_rne(float x) {
    unsigned b = __float_as_uint(x);
    return (b + 0x7fffu + ((b >> 16) & 1u)) >> 16;
}
__device__ __forceinline__ float rcpf(float x) { return __builtin_amdgcn_rcpf(x); }

template<int CTRL>
__device__ __forceinline__ float dppf(float x) {
    return __int_as_float(__builtin_amdgcn_update_dpp(
        __float_as_int(x), __float_as_int(x), CTRL, 0xF, 0xF, false));
}
// fused wave64 sum(s) + min(m)
__device__ __forceinline__ void wave_red2(float& s, float& m) {
    s += dppf<0x121>(s); m = fminf(m, dppf<0x121>(m));
    s += dppf<0x122>(s); m = fminf(m, dppf<0x122>(m));
    s += dppf<0x124>(s); m = fminf(m, dppf<0x124>(m));
    s += dppf<0x128>(s); m = fminf(m, dppf<0x128>(m));
    s += __int_as_float(__builtin_amdgcn_ds_swizzle(__float_as_int(s), 0x401F));
    m = fminf(m, __int_as_float(__builtin_amdgcn_ds_swizzle(__float_as_int(m), 0x401F)));
    float s0 = __int_as_float(__builtin_amdgcn_readlane(__float_as_int(s), 0));
    float s1 = __int_as_float(__builtin_amdgcn_readlane(__float_as_int(s), 32));
    s = s0 + s1;
    float m0 = __int_as_float(__builtin_amdgcn_readlane(__float_as_int(m), 0));
    float m1 = __int_as_float(__builtin_amdgcn_readlane(__float_as_int(m), 32));
    m = fminf(m0, m1);
}

__device__ __forceinline__ float min8v(const float* a) {
    float4 x0 = *(const float4*)a, x1 = *(const float4*)(a + 4);
    return fminf(fminf(fminf(x0.x, x0.y), fminf(x0.z, x0.w)),
                 fminf(fminf(x1.x, x1.y), fminf(x1.z, x1.w)));
}
__device__ __forceinline__ float sum8v(const float* a) {
    float4 x0 = *(const float4*)a, x1 = *(const float4*)(a + 4);
    return ((x0.x + x0.y) + (x0.z + x0.w)) + ((x1.x + x1.y) + (x1.z + x1.w));
}

// ---------------- pooling: softmax(x) and one-hot(y), adaptive-avg-pool 8x8 ----------------
__global__ __launch_bounds__(256) void pool_kernel(const float* __restrict__ x,
                                                   const int* __restrict__ y,
                                                   float* __restrict__ pooled) {
    int blk = blockIdx.x;              // 0..95
    int img = blk >> 2;                // 0..23
    int cell = ((blk & 3) << 8) | threadIdx.x;
    int gi = cell >> 5, gj = cell & 31;
    const float L2E = 1.4426950408889634f;
    float acc = 0.f;
    if (img < 12) {
        int b = img / 3, c = img % 3 + 1;
        const float* xb = x + (size_t)b * 262144 + (size_t)gi * 2048 + gj * 8;
        for (int pi = 0; pi < 8; ++pi) {
            const float* xr = xb + pi * 256;
            #pragma unroll
            for (int ph = 0; ph < 2; ++ph) {
                float4 c0 = *(const float4*)(xr + ph * 4);
                float4 c1 = *(const float4*)(xr + ph * 4 + 65536);
                float4 c2 = *(const float4*)(xr + ph * 4 + 131072);
                float4 c3 = *(const float4*)(xr + ph * 4 + 196608);
                const float* f0 = (const float*)&c0;
                const float* f1 = (const float*)&c1;
                const float* f2 = (const float*)&c2;
                const float* f3 = (const float*)&c3;
                #pragma unroll
                for (int k = 0; k < 4; ++k) {
                    float e0 = exp2f(f0[k] * L2E), e1 = exp2f(f1[k] * L2E);
                    float e2 = exp2f(f2[k] * L2E), e3 = exp2f(f3[k] * L2E);
                    float ec = (c == 1) ? e1 : (c == 2) ? e2 : e3;
                    acc += ec / (e0 + e1 + e2 + e3);
                }
            }
        }
    } else {
        int tt = img - 12;
        int b = tt / 3, c = tt % 3 + 1;
        const int* yb = y + (size_t)b * 65536 + (size_t)gi * 2048 + gj * 8;
        int cnt = 0;
        for (int pi = 0; pi < 8; ++pi) {
            const int* yr = yb + pi * 256;
            #pragma unroll
            for (int pj = 0; pj < 8; ++pj) cnt += (yr[pj] == c) ? 1 : 0;
        }
        acc = (float)cnt;
    }
    pooled[img * NPIX + cell] = acc * (1.f / 64.f);
}

// ---------------- bitonic sort of 2048 u64 keys, register phases for j<=2 ----------------
__device__ __forceinline__ void cex(unsigned long long& a, unsigned long long& b, bool up) {
    if ((a > b) == up) { unsigned long long t = a; a = b; b = t; }
}
__device__ void bitonic2048_reg(unsigned long long* keys, int tid, bool asc) {
    int i0 = tid << 2;   // thread owns elements i0..i0+3
    for (int k = 2; k <= NPAD; k <<= 1) {
        for (int j = k >> 1; j >= 4; j >>= 1) {
            #pragma unroll
            for (int rep = 0; rep < 4; ++rep) {
                int ii = tid + rep * 512;
                int l = ii ^ j;
                if (l > ii) {
                    unsigned long long a = keys[ii], b = keys[l];
                    bool up = (((ii & k) == 0) == asc);
                    if ((a > b) == up) { keys[ii] = b; keys[l] = a; }
                }
            }
            __syncthreads();
        }
        // j = 2 (k>=4) and j = 1 in registers; quad direction uniform for k>=4
        unsigned long long e0 = keys[i0], e1 = keys[i0 + 1], e2 = keys[i0 + 2], e3 = keys[i0 + 3];
        bool upq = (((i0 & k) == 0) == asc);
        if (k >= 4) {
            cex(e0, e2, upq); cex(e1, e3, upq);
            cex(e0, e1, upq); cex(e2, e3, upq);
        } else {   // k == 2: j=1 only, direction alternates within the quad
            cex(e0, e1, asc);
            cex(e2, e3, !asc);
        }
        keys[i0] = e0; keys[i0 + 1] = e1; keys[i0 + 2] = e2; keys[i0 + 3] = e3;
        __syncthreads();
    }
}

// ---------------- persistence diagrams (H0 sublevel / H1 via superlevel duality) ------------
// Serial UF body byte-identical to r9/r10 (absmax 0.0). New: claim-based parallel merge
// commit — merges whose snapshot root-pair is untouched by any other in-batch edge commit
// in parallel (pair values exact: births are init-only, birth[root]==v_[root]); conflicting
// edges fall through to the serial scan. pbd output is bit-identical.
__global__ __launch_bounds__(512) void diag_kernel(const float* __restrict__ pooled,
                                                   float* __restrict__ diag) {
    __shared__ float v_[NPIX];
    __shared__ unsigned long long keys[NPAD];
    __shared__ unsigned long long PB[NPIX];      // low 32: parent, high 32: birth (f32 bits)
    __shared__ unsigned euv[NPAD];               // u | v<<16 per edge index
    __shared__ unsigned long long pbd[NEDGE];    // low: pb bits, high: pd bits
    __shared__ unsigned long long snap[132];     // wbits<<22 | (ra+1)<<11 | (rb+1); 0 = done
    __shared__ unsigned claimA[NPIX];            // per-root earliest-claiming batch slot
    __shared__ unsigned histAll[2048];           // 8 wave-copies x 256 bins
    __shared__ float redA[8], redB[8];
    __shared__ float svmin, svmax;
    __shared__ unsigned long long s_prefix, s_T;
    __shared__ unsigned s_need, s_done, s_outcnt;

    int run = blockIdx.x;      // 0..47
    int img = run >> 1, filt = run & 1;
    int tid = threadIdx.x;
    int wv = tid >> 6;
    const float* m = pooled + img * NPIX;

    for (int i = tid; i < NPIX; i += 512) {
        float val = m[i];
        v_[i] = filt ? -val : val;
    }
    __syncthreads();
    // min/max (for the essential H0 class)
    float mn = INFINITY, mx = -INFINITY;
    for (int i = tid; i < NPIX; i += 512) { float vv = v_[i]; mn = fminf(mn, vv); mx = fmaxf(mx, vv); }
    for (int o = 32; o; o >>= 1) { mn = fminf(mn, __shfl_xor(mn, o)); mx = fmaxf(mx, __shfl_xor(mx, o)); }
    if ((tid & 63) == 0) { redA[wv] = mn; redB[wv] = mx; }
    __syncthreads();
    if (tid == 0) {
        float a = INFINITY, b = -INFINITY;
        for (int i2 = 0; i2 < 8; ++i2) { a = fminf(a, redA[i2]); b = fmaxf(b, redB[i2]); }
        svmin = a; svmax = b;
    }
    // edge keys: stable sort by (weight, edge index) — replicates jnp.argsort (stable)
    for (int e = tid; e < NPAD; e += 512) {
        unsigned long long key;
        unsigned uv = 0;
        if (e < NEDGE) {
            int u, vv;
            if (e < 992) { int r = e / 31; u = e + r; vv = u + 1; }   // horizontal
            else         { u = e - 992;   vv = u + 32; }              // vertical
            float w = fmaxf(v_[u], v_[vv]);
            unsigned int bw = __float_as_uint(w);
            bw = (bw & 0x80000000u) ? ~bw : (bw | 0x80000000u);       // orderable float bits
            key = ((unsigned long long)bw << 11) | (unsigned int)e;
            uv = (unsigned)u | ((unsigned)vv << 16);
        } else key = ~0ULL;
        keys[e] = key;
        euv[e] = uv;
    }
    for (int i = tid; i < NPIX; i += 512)
        PB[i] = ((unsigned long long)__float_as_uint(v_[i]) << 32) | (unsigned)i;
    __syncthreads();
    bitonic2048_reg(keys, tid, true);   // ascending; ends with a barrier

    // Kruskal/union-find with elder rule, batch-snapshot + parallel-commit structure.
    unsigned* PBlo = (unsigned*)PB;
    for (int base = 0; base < NEDGE; base += 128) {
        // reset claims + parallel pointer-jumping compression (roots/births untouched)
        for (int i = tid; i < NPIX; i += 512) claimA[i] = 0xFFFFFFFFu;
        if (base) {
            for (int rd = 0; rd < 4; ++rd) {
                for (int i = tid; i < NPIX; i += 512) {
                    unsigned pp = PBlo[2 * i];
                    unsigned gg = PBlo[2 * pp];
                    PBlo[2 * i] = gg;           // benign race: result is always an ancestor
                }
            }
        }
        __syncthreads();
        int bend = (base + 128 < NEDGE) ? base + 128 : NEDGE;
        int bcnt = bend - base;
        // parallel precheck: resolve snapshot roots; trivial pairs emitted; merges claim roots
        if (tid < bcnt) {
            int kk = base + tid;
            unsigned long long key = keys[kk];
            int e = (int)(key & 2047ULL);
            unsigned bw = (unsigned)(key >> 11);
            unsigned uv = euv[e];
            int ra = (int)(uv & 0xffffu), rb = (int)(uv >> 16);
            unsigned pp = PBlo[2 * ra];
            while (pp != (unsigned)ra) { ra = (int)pp; pp = PBlo[2 * ra]; }
            unsigned p2 = PBlo[2 * rb];
            while (p2 != (unsigned)rb) { rb = (int)p2; p2 = PBlo[2 * rb]; }
            if (ra == rb) {
                unsigned wb = (bw & 0x80000000u) ? (bw & 0x7fffffffu) : ~bw;
                pbd[kk] = (unsigned long long)wb | ((unsigned long long)wb << 32);
                snap[tid] = 0ULL;                                // done (trivial)
            } else {
                snap[tid] = ((unsigned long long)bw << 22)
                          | ((unsigned)(ra + 1) << 11) | (unsigned)(rb + 1);
                atomicMin(&claimA[ra], (unsigned)tid);
                atomicMin(&claimA[rb], (unsigned)tid);
            }
        }
        __syncthreads();
        // parallel commit: edges owning BOTH root claims are isolated -> exact to commit now
        if (tid < bcnt) {
            unsigned long long sc = snap[tid];
            if ((unsigned)(sc & 0x3FFFFFu)) {
                int ra = (int)((sc >> 11) & 0x7FFu) - 1;
                int rb = (int)(sc & 0x7FFu) - 1;
                if (claimA[ra] == (unsigned)tid && claimA[rb] == (unsigned)tid) {
                    unsigned ob = (unsigned)(sc >> 22);
                    float w = __uint_as_float((ob & 0x80000000u) ? (ob & 0x7fffffffu) : ~ob);
                    float bu = v_[ra], bv = v_[rb];      // birth[root] == v_[root] (init-only)
                    bool uo = (bu <= bv);                // tie -> root on u's side
                    int older = uo ? ra : rb;
                    int younger = uo ? rb : ra;
                    PBlo[2 * younger] = (unsigned)older;
                    float pb_ = fmaxf(bu, bv);
                    pbd[base + tid] = (unsigned long long)__float_as_uint(pb_)
                                    | ((unsigned long long)__float_as_uint(w) << 32);
                    snap[tid] = 0ULL;                    // done (parallel-committed)
                }
            }
        }
        __syncthreads();
        // serial elder-rule scan over remaining conflicting merges (r9-exact body)
        if (tid == 0) {
            unsigned long long sc = snap[0];
            for (int i = 0; i < bcnt; ++i) {
                unsigned long long sn = snap[i + 1];             // read-only prefetch, no hazard
                if ((unsigned)(sc & 0x3FFFFFu)) {
                    unsigned ob = (unsigned)(sc >> 22);
                    float w = __uint_as_float((ob & 0x80000000u) ? (ob & 0x7fffffffu) : ~ob);
                    int a = (int)((sc >> 11) & 0x7FFu) - 1;
                    int b = (int)(sc & 0x7FFu) - 1;
                    unsigned long long qa = PB[a], qb = PB[b];
                    int pa = (int)(unsigned)qa, pb = (int)(unsigned)qb;
                    while (pa != a || pb != b) {
                        if (pa != a) {
                            unsigned long long na = PB[pa];
                            int ga = (int)(unsigned)na;
                            PBlo[2 * a] = (unsigned)ga;     // path-halving compression
                            a = pa; pa = ga; qa = na;
                        }
                        if (pb != b) {
                            unsigned long long nb = PB[pb];
                            int gb = (int)(unsigned)nb;
                            PBlo[2 * b] = (unsigned)gb;
                            b = pb; pb = gb; qb = nb;
                        }
                    }
                    float pb_, pd_;
                    if (a != b) {
                        float bu = __uint_as_float((unsigned)(qa >> 32));
                        float bv = __uint_as_float((unsigned)(qb >> 32));
                        bool uo = (bu <= bv);                 // tie -> root on u's side
                        int older = uo ? a : b;
                        int younger = uo ? b : a;
                        pb_ = fmaxf(bu, bv); pd_ = w;         // younger component dies
                        PBlo[2 * younger] = (unsigned)older;  // birth[older] already the min
                    } else { pb_ = w; pd_ = w; }              // became trivial within batch
                    pbd[base + i] = (unsigned long long)__float_as_uint(pb_)
                                  | ((unsigned long long)__float_as_uint(pd_) << 32);
                }
                sc = sn;
            }
        }
        __syncthreads();
    }

    // ---- top-k selection by (persistence, lower index) via radix-select ----
    // Downstream Sinkhorn is index-order-invariant, so only the selected SET matters.
    int count = filt ? NEDGE : (NEDGE + 1);
    for (int k = tid; k < NPAD; k += 512) {
        unsigned long long key = 0ULL;
        if (k < count) {
            float pers;
            if (k < NEDGE) {
                unsigned long long pd2 = pbd[k];
                pers = __uint_as_float((unsigned)(pd2 >> 32)) - __uint_as_float((unsigned)pd2);
            } else pers = svmax - svmin;
            key = ((unsigned long long)__float_as_uint(pers) << 32) | (unsigned int)(2047 - k);
        }
        keys[k] = key;
    }
    if (tid == 0) { s_prefix = 0ULL; s_T = 0ULL; s_need = KTOP; s_done = 0; s_outcnt = 0; }
    __syncthreads();

    for (int rnd = 0; rnd < 8; ++rnd) {
        for (int i = tid; i < 2048; i += 512) histAll[i] = 0;
        __syncthreads();
        if (!s_done) {
            int shift = 56 - 8 * rnd;
            unsigned long long pref = s_prefix;
            for (int k = tid; k < NPAD; k += 512) {
                unsigned long long key = keys[k];
                bool act = (rnd == 0) || ((key >> (shift + 8)) == (pref >> (shift + 8)));
                if (act) atomicAdd(&histAll[wv * 256 + (unsigned)((key >> shift) & 255ULL)], 1u);
            }
        }
        __syncthreads();
        if (wv == 0) {
            if (!s_done) {
                int l64 = tid;            // lane id within wave 0
                int shift = 56 - 8 * rnd;
                unsigned c0 = 0, c1 = 0, c2 = 0, c3 = 0;
                #pragma unroll
                for (int cp = 0; cp < 8; ++cp) {
                    const unsigned* h = histAll + cp * 256 + 4 * l64;
                    c0 += h[0]; c1 += h[1]; c2 += h[2]; c3 += h[3];
                }
                unsigned s3 = c3, s2 = c2 + s3, s1 = c1 + s2, s0 = c0 + s1;
                // wave-wide suffix sum of lane totals (s0)
                unsigned acc2 = s0;
                #pragma unroll
                for (int o = 1; o < 64; o <<= 1) {
                    unsigned v2 = __shfl_down(acc2, o);
                    if (l64 + o < 64) acc2 += v2;
                }
                unsigned above = acc2 - s0;                 // sum over lanes > l64
                unsigned Sn[5] = {above + s0, above + s1, above + s2, above + s3, above};
                unsigned need = s_need;
                #pragma unroll
                for (int q2 = 0; q2 < 4; ++q2) {
                    if (Sn[q2] >= need && Sn[q2 + 1] < need) {     // exactly one lane/bin fires
                        unsigned bstar = 4 * l64 + q2;
                        if (Sn[q2] == need) {
                            s_T = s_prefix | ((unsigned long long)bstar << shift);
                            s_done = 1;
                        } else {
                            s_prefix = s_prefix | ((unsigned long long)bstar << shift);
                            s_need = need - Sn[q2 + 1];
                        }
                    }
                }
            }
        }
        __syncthreads();
    }

    // compact selected (key >= T) and write output; order within diag is irrelevant downstream
    {
        unsigned long long T = s_T;
        for (int k = tid; k < NPAD; k += 512) {
            unsigned long long key = keys[k];
            if (key >= T && key != 0ULL) {
                int pos = (int)atomicAdd(&s_outcnt, 1u);
                int kk = 2047 - (int)(key & 0xffffffffULL);
                float b_, d_;
                if (kk < NEDGE) {
                    unsigned long long pd2 = pbd[kk];
                    b_ = __uint_as_float((unsigned)pd2);
                    d_ = __uint_as_float((unsigned)(pd2 >> 32));
                } else { b_ = svmin; d_ = svmax; }
                float ob, od;
                if (!filt) { ob = b_;  od = d_;  }       // H0 pairs
                else       { ob = -d_; od = -b_; }       // H1 = negated superlevel H0
                diag[((img * 4) + filt * 2 + 0) * KTOP + pos] = ob;
                diag[((img * 4) + filt * 2 + 1) * KTOP + pos] = od;
            }
        }
    }
}

// ---------------- entropic Sinkhorn: MFMA matvec + fold normalization ----------------------
// Byte-identical to the round-8/9/10 version (verified absmax 0.0).
__global__ __launch_bounds__(512) void sink_kernel(const float* __restrict__ diag,
                                                   float* __restrict__ wres) {
    __shared__ float2 sPA[KTOP], sPB[KTOP];
    __shared__ float sda[KTOP], sdb[KTOP];
    __shared__ float swa[KTOP], swb[KTOP];
    __shared__ __align__(16) unsigned ug_bf[128];    // 256 bf16
    __shared__ __align__(16) unsigned uf_bf[128];
    __shared__ __align__(16) float uf32[KTOP], ug32[KTOP];
    __shared__ __align__(16) float minF[8], accTF[8], minG[8], accTG[8];
    __shared__ __align__(16) float pm[8];
    __shared__ float s_sig, s_invsig;

    int p = blockIdx.x;            // 0..23
    int img = p % 12, dim = p / 12;
    int t = threadIdx.x;
    int lane = t & 63, w = t >> 6;         // wave 0..7
    int lr = lane & 15, lg = lane >> 4;    // col-lane, k-group
    int r = t >> 1, q = t & 1, jb = q * 128;   // mapping for maxC / final cost

    const float* ab  = diag + ((img * 4) + dim * 2) * KTOP;
    const float* ad  = ab + KTOP;
    const float* bbp = diag + (((12 + img) * 4) + dim * 2) * KTOP;
    const float* bdp = bbp + KTOP;

    if (t < KTOP) {
        float a0 = ab[t], a1 = ad[t];
        float b0 = bbp[t], b1 = bdp[t];
        sPA[t] = make_float2(a0, a1);
        sPB[t] = make_float2(b0, b1);
        sda[t] = 0.5f * (a1 - a0);
        sdb[t] = 0.5f * (b1 - b0);
    }
    if (t < 128) ug_bf[t] = 0x3F803F80u;   // u = 1.0 (bf16 pair)
    __syncthreads();

    // maxC (unscaled)
    {
        float2 A = sPA[r];
        float lmax = 0.f;
        for (int jj = 0; jj < 128; ++jj) {
            float2 B = sPB[jb + jj];
            lmax = fmaxf(lmax, fmaxf(fabsf(A.x - B.x), fabsf(A.y - B.y)));
        }
        if (t < KTOP) lmax = fmaxf(lmax, fmaxf(sda[t], sdb[t]));
        for (int o = 32; o; o >>= 1) lmax = fmaxf(lmax, __shfl_xor(lmax, o));
        if (lane == 0) pm[w] = lmax;
    }
    __syncthreads();
    if (t == 0) {
        float mc = 0.f;
        for (int i = 0; i < 8; ++i) mc = fmaxf(mc, pm[i]);
        float eps = 0.02f * fmaxf(mc, 1e-6f);
        s_sig = 1.4426950408889634f / eps;        // log2(e)/eps
        s_invsig = eps * 0.6931471805599453f;     // eps*ln2
    }
    __syncthreads();
    {
        float sig = s_sig;
        if (t < KTOP) {
            float2 a2 = sPA[t], b2 = sPB[t];
            sPA[t] = make_float2(a2.x * sig, a2.y * sig);
            sPB[t] = make_float2(b2.x * sig, b2.y * sig);
            float da2 = sda[t] * sig, db2 = sdb[t] * sig;
            sda[t] = da2; sdb[t] = db2;
            swa[t] = exp2f(-da2); swb[t] = exp2f(-db2);
        }
    }
    __syncthreads();

    // Build A-fragments: Kf (rows of K) and Kg (rows of K^T), bf16, constant across iters.
    bf16x8_t KfA0[8], KfA1[8], KgA0[8], KgA1[8];
    {
        float2 Af0 = sPA[w * 32 + lr];
        float2 Af1 = sPA[w * 32 + 16 + lr];
        float2 Bg0 = sPB[w * 32 + lr];
        float2 Bg1 = sPB[w * 32 + 16 + lr];
        #pragma unroll
        for (int ks = 0; ks < 8; ++ks) {
            #pragma unroll
            for (int jj = 0; jj < 8; ++jj) {
                int b = ks * 32 + lg * 8 + jj;
                float2 Pb = sPB[b];
                KfA0[ks][jj] = (short)bf_rne(exp2f(-fmaxf(fabsf(Af0.x - Pb.x), fabsf(Af0.y - Pb.y))));
                KfA1[ks][jj] = (short)bf_rne(exp2f(-fmaxf(fabsf(Af1.x - Pb.x), fabsf(Af1.y - Pb.y))));
                float2 Pa = sPA[b];
                KgA0[ks][jj] = (short)bf_rne(exp2f(-fmaxf(fabsf(Pa.x - Bg0.x), fabsf(Pa.y - Bg0.y))));
                KgA1[ks][jj] = (short)bf_rne(exp2f(-fmaxf(fabsf(Pa.x - Bg1.x), fabsf(Pa.y - Bg1.y))));
            }
        }
    }
    // Diagonal weights in D layout: row = w*32 + tt*16 + lg*4 + reg
    float wa0[4], wa1[4], wb0[4], wb1[4];
    #pragma unroll
    for (int g2 = 0; g2 < 4; ++g2) {
        wa0[g2] = swa[w * 32 + lg * 4 + g2];
        wa1[g2] = swa[w * 32 + 16 + lg * 4 + g2];
        wb0[g2] = swb[w * 32 + lg * 4 + g2];
        wb1[g2] = swb[w * 32 + 16 + lg * 4 + g2];
    }

    float cg = 1.f, cf = 1.f, uG2s = 1.f, uF2s = 1.f;
    f32x4_t ugs0 = {1.f, 1.f, 1.f, 1.f}, ugs1 = {1.f, 1.f, 1.f, 1.f};
    f32x4_t ufs0 = {0.f, 0.f, 0.f, 0.f}, ufs1 = {0.f, 0.f, 0.f, 0.f};

    for (int it = 0; it < NITER; ++it) {
        // ---- f phase ----
        if (it) {
            cg = min8v(minG);
            uG2s = rcpf(cf * (sum8v(accTG) + 256.f * uF2s));
        }
        {
            bf16x8_t Bf[8];
            #pragma unroll
            for (int ks = 0; ks < 8; ++ks) Bf[ks] = ((const bf16x8_t*)ug_bf)[ks * 4 + lg];
            f32x4_t a0 = {0.f, 0.f, 0.f, 0.f}, a1 = {0.f, 0.f, 0.f, 0.f};
            #pragma unroll
            for (int ks = 0; ks < 8; ++ks) {
                a0 = __builtin_amdgcn_mfma_f32_16x16x32_bf16(KfA0[ks], Bf[ks], a0, 0, 0, 0);
                a1 = __builtin_amdgcn_mfma_f32_16x16x32_bf16(KfA1[ks], Bf[ks], a1, 0, 0, 0);
            }
            float mv = INFINITY, tv = 0.f;
            #pragma unroll
            for (int g2 = 0; g2 < 4; ++g2) {
                float R0 = cg * (a0[g2] + 256.f * uG2s * wa0[g2]);
                float R1 = cg * (a1[g2] + 256.f * uG2s * wa1[g2]);
                ufs0[g2] = rcpf(R0); ufs1[g2] = rcpf(R1);
                mv = fminf(mv, fminf(R0, R1));
                tv += ugs0[g2] * wb0[g2] + ugs1[g2] * wb1[g2];   // T_f from OLD ug
            }
            if (lr == 0) {
                uint2 v0, v1;
                v0.x = bf_rne(ufs0[0]) | (bf_rne(ufs0[1]) << 16);
                v0.y = bf_rne(ufs0[2]) | (bf_rne(ufs0[3]) << 16);
                v1.x = bf_rne(ufs1[0]) | (bf_rne(ufs1[1]) << 16);
                v1.y = bf_rne(ufs1[2]) | (bf_rne(ufs1[3]) << 16);
                ((uint2*)uf_bf)[w * 8 + lg] = v0;
                ((uint2*)uf_bf)[w * 8 + 4 + lg] = v1;
            }
            wave_red2(tv, mv);
            if (lane == 0) { accTF[w] = tv * 0.0625f; minF[w] = mv; }   // rows duplicated x16
        }
        __syncthreads();
        // ---- g phase ----
        cf = min8v(minF);
        uF2s = rcpf(cg * (sum8v(accTF) + 256.f * uG2s));
        {
            bf16x8_t Bf[8];
            #pragma unroll
            for (int ks = 0; ks < 8; ++ks) Bf[ks] = ((const bf16x8_t*)uf_bf)[ks * 4 + lg];
            f32x4_t a0 = {0.f, 0.f, 0.f, 0.f}, a1 = {0.f, 0.f, 0.f, 0.f};
            #pragma unroll
            for (int ks = 0; ks < 8; ++ks) {
                a0 = __builtin_amdgcn_mfma_f32_16x16x32_bf16(KgA0[ks], Bf[ks], a0, 0, 0, 0);
                a1 = __builtin_amdgcn_mfma_f32_16x16x32_bf16(KgA1[ks], Bf[ks], a1, 0, 0, 0);
            }
            float mv = INFINITY, tv = 0.f;
            #pragma unroll
            for (int g2 = 0; g2 < 4; ++g2) {
                float Q0 = cf * (a0[g2] + 256.f * uF2s * wb0[g2]);
                float Q1 = cf * (a1[g2] + 256.f * uF2s * wb1[g2]);
                ugs0[g2] = rcpf(Q0); ugs1[g2] = rcpf(Q1);
                mv = fminf(mv, fminf(Q0, Q1));
                tv += ufs0[g2] * wa0[g2] + ufs1[g2] * wa1[g2];   // T_g from NEW uf
            }
            if (lr == 0) {
                uint2 v0, v1;
                v0.x = bf_rne(ugs0[0]) | (bf_rne(ugs0[1]) << 16);
                v0.y = bf_rne(ugs0[2]) | (bf_rne(ugs0[3]) << 16);
                v1.x = bf_rne(ugs1[0]) | (bf_rne(ugs1[1]) << 16);
                v1.y = bf_rne(ugs1[2]) | (bf_rne(ugs1[3]) << 16);
                ((uint2*)ug_bf)[w * 8 + lg] = v0;
                ((uint2*)ug_bf)[w * 8 + 4 + lg] = v1;
            }
            wave_red2(tv, mv);
            if (lane == 0) { accTG[w] = tv * 0.0625f; minG[w] = mv; }
        }
        __syncthreads();
    }
    // final G2 (after last g update); overall plan scale = cf
    float uG2f = rcpf(cf * (sum8v(accTG) + 256.f * uF2s));
    // publish exact f32 potentials for the cost epilogue
    if (lr == 0) {
        ((f32x4_t*)uf32)[w * 8 + lg] = ufs0;
        ((f32x4_t*)uf32)[w * 8 + 4 + lg] = ufs1;
        ((f32x4_t*)ug32)[w * 8 + lg] = ugs0;
        ((f32x4_t*)ug32)[w * 8 + 4 + lg] = ugs1;
    }
    __syncthreads();

    // ---- final cost sum(P*C): P_ij = cf * ufs_i * K_ij * ugs_j,  C = Mhat*invsig ----
    float accv = 0.f;
    {
        float2 Apt = sPA[r];
        float ufr = uf32[r];
        #pragma unroll 8
        for (int jj = 0; jj < 128; ++jj) {
            int j = jb + jj;
            float2 B = sPB[j];
            float Mh = fmaxf(fabsf(Apt.x - B.x), fabsf(Apt.y - B.y));
            float kv = __uint_as_float(bf_rne(exp2f(-Mh)) << 16);   // same bf16 K as iterations
            accv += ((ufr * kv) * ug32[j]) * Mh;
        }
        if (q == 0) accv += 256.f * ((ufr * swa[r]) * uG2f) * sda[r];
        else        accv += 256.f * ((uF2s * swb[r]) * ug32[r]) * sdb[r];
    }
    accv *= cf;
    for (int o = 32; o; o >>= 1) accv += __shfl_xor(accv, o);
    if (lane == 0) pm[w] = accv;
    __syncthreads();
    if (t == 0) {
        float tot = 0.f;
        for (int i = 0; i < 8; ++i) tot += pm[i];
        wres[p] = tot * s_invsig;   // back to natural units
    }
}

__global__ void finalize_kernel(const float* __restrict__ wres, float* __restrict__ out) {
    if (threadIdx.x == 0) {
        float s = 0.f;
        for (int i = 0; i < 24; ++i) s += wres[i];
        out[0] = s * 0.25f;        // / B
    }
}

extern "C" void kernel_launch(void* const* d_in, const int* in_sizes, int n_in,
                              void* d_out, int out_size, void* d_ws, size_t ws_size,
                              hipStream_t stream) {
    const float* x = (const float*)d_in[0];   // [4,4,256,256] f32
    const int* y = (const int*)d_in[1];       // [4,1,256,256] i32
    float* ws = (float*)d_ws;
    float* pooled = ws;                        // 24*1024 floats
    float* diag = pooled + 24 * NPIX;          // 24*4*256 floats
    float* wres = diag + 24 * 4 * KTOP;        // 24 floats

    pool_kernel<<<96, 256, 0, stream>>>(x, y, pooled);
    diag_kernel<<<48, 512, 0, stream>>>(pooled, diag);
    sink_kernel<<<24, 512, 0, stream>>>(diag, wres);
    finalize_kernel<<<1, 64, 0, stream>>>(wres, (float*)d_out);
}

// Round 13
// 767.773 us; speedup vs baseline: 1.0652x; 1.0652x over previous
//
#include <hip/hip_runtime.h>
#include <cmath>

#define NPIX 1024
#define NEDGE 1984
#define NPAD 2048
#define KTOP 256
#define NITER 150

typedef __attribute__((ext_vector_type(8))) short bf16x8_t;   // 8 bf16 = 4 VGPRs
typedef __attribute__((ext_vector_type(4))) float f32x4_t;

__device__ __forceinline__ unsigned bf_rne(float x) {
    unsigned b = __float_as_uint(x);
    return (b + 0x7fffu + ((b >> 16) & 1u)) >> 16;
}
__device__ __forceinline__ float rcpf(float x) { return __builtin_amdgcn_rcpf(x); }

template<int CTRL>
__device__ __forceinline__ float dppf(float x) {
    return __int_as_float(__builtin_amdgcn_update_dpp(
        __float_as_int(x), __float_as_int(x), CTRL, 0xF, 0xF, false));
}
// fused wave64 sum(s) + min(m)
__device__ __forceinline__ void wave_red2(float& s, float& m) {
    s += dppf<0x121>(s); m = fminf(m, dppf<0x121>(m));
    s += dppf<0x122>(s); m = fminf(m, dppf<0x122>(m));
    s += dppf<0x124>(s); m = fminf(m, dppf<0x124>(m));
    s += dppf<0x128>(s); m = fminf(m, dppf<0x128>(m));
    s += __int_as_float(__builtin_amdgcn_ds_swizzle(__float_as_int(s), 0x401F));
    m = fminf(m, __int_as_float(__builtin_amdgcn_ds_swizzle(__float_as_int(m), 0x401F)));
    float s0 = __int_as_float(__builtin_amdgcn_readlane(__float_as_int(s), 0));
    float s1 = __int_as_float(__builtin_amdgcn_readlane(__float_as_int(s), 32));
    s = s0 + s1;
    float m0 = __int_as_float(__builtin_amdgcn_readlane(__float_as_int(m), 0));
    float m1 = __int_as_float(__builtin_amdgcn_readlane(__float_as_int(m), 32));
    m = fminf(m0, m1);
}

__device__ __forceinline__ float min8v(const float* a) {
    float4 x0 = *(const float4*)a, x1 = *(const float4*)(a + 4);
    return fminf(fminf(fminf(x0.x, x0.y), fminf(x0.z, x0.w)),
                 fminf(fminf(x1.x, x1.y), fminf(x1.z, x1.w)));
}
__device__ __forceinline__ float sum8v(const float* a) {
    float4 x0 = *(const float4*)a, x1 = *(const float4*)(a + 4);
    return ((x0.x + x0.y) + (x0.z + x0.w)) + ((x1.x + x1.y) + (x1.z + x1.w));
}

// ---------------- pooling: softmax(x) and one-hot(y), adaptive-avg-pool 8x8 ----------------
__global__ __launch_bounds__(256) void pool_kernel(const float* __restrict__ x,
                                                   const int* __restrict__ y,
                                                   float* __restrict__ pooled) {
    int blk = blockIdx.x;              // 0..95
    int img = blk >> 2;                // 0..23
    int cell = ((blk & 3) << 8) | threadIdx.x;
    int gi = cell >> 5, gj = cell & 31;
    const float L2E = 1.4426950408889634f;
    float acc = 0.f;
    if (img < 12) {
        int b = img / 3, c = img % 3 + 1;
        const float* xb = x + (size_t)b * 262144 + (size_t)gi * 2048 + gj * 8;
        for (int pi = 0; pi < 8; ++pi) {
            const float* xr = xb + pi * 256;
            #pragma unroll
            for (int ph = 0; ph < 2; ++ph) {
                float4 c0 = *(const float4*)(xr + ph * 4);
                float4 c1 = *(const float4*)(xr + ph * 4 + 65536);
                float4 c2 = *(const float4*)(xr + ph * 4 + 131072);
                float4 c3 = *(const float4*)(xr + ph * 4 + 196608);
                const float* f0 = (const float*)&c0;
                const float* f1 = (const float*)&c1;
                const float* f2 = (const float*)&c2;
                const float* f3 = (const float*)&c3;
                #pragma unroll
                for (int k = 0; k < 4; ++k) {
                    float e0 = exp2f(f0[k] * L2E), e1 = exp2f(f1[k] * L2E);
                    float e2 = exp2f(f2[k] * L2E), e3 = exp2f(f3[k] * L2E);
                    float ec = (c == 1) ? e1 : (c == 2) ? e2 : e3;
                    acc += ec / (e0 + e1 + e2 + e3);
                }
            }
        }
    } else {
        int tt = img - 12;
        int b = tt / 3, c = tt % 3 + 1;
        const int* yb = y + (size_t)b * 65536 + (size_t)gi * 2048 + gj * 8;
        int cnt = 0;
        for (int pi = 0; pi < 8; ++pi) {
            const int* yr = yb + pi * 256;
            #pragma unroll
            for (int pj = 0; pj < 8; ++pj) cnt += (yr[pj] == c) ? 1 : 0;
        }
        acc = (float)cnt;
    }
    pooled[img * NPIX + cell] = acc * (1.f / 64.f);
}

// ---------------- bitonic sort of 2048 u64 keys, register phases for j<=2 ----------------
__device__ __forceinline__ void cex(unsigned long long& a, unsigned long long& b, bool up) {
    if ((a > b) == up) { unsigned long long t = a; a = b; b = t; }
}
__device__ void bitonic2048_reg(unsigned long long* keys, int tid, bool asc) {
    int i0 = tid << 2;   // thread owns elements i0..i0+3
    for (int k = 2; k <= NPAD; k <<= 1) {
        for (int j = k >> 1; j >= 4; j >>= 1) {
            #pragma unroll
            for (int rep = 0; rep < 4; ++rep) {
                int ii = tid + rep * 512;
                int l = ii ^ j;
                if (l > ii) {
                    unsigned long long a = keys[ii], b = keys[l];
                    bool up = (((ii & k) == 0) == asc);
                    if ((a > b) == up) { keys[ii] = b; keys[l] = a; }
                }
            }
            __syncthreads();
        }
        // j = 2 (k>=4) and j = 1 in registers; quad direction uniform for k>=4
        unsigned long long e0 = keys[i0], e1 = keys[i0 + 1], e2 = keys[i0 + 2], e3 = keys[i0 + 3];
        bool upq = (((i0 & k) == 0) == asc);
        if (k >= 4) {
            cex(e0, e2, upq); cex(e1, e3, upq);
            cex(e0, e1, upq); cex(e2, e3, upq);
        } else {   // k == 2: j=1 only, direction alternates within the quad
            cex(e0, e1, asc);
            cex(e2, e3, !asc);
        }
        keys[i0] = e0; keys[i0 + 1] = e1; keys[i0 + 2] = e2; keys[i0 + 3] = e3;
        __syncthreads();
    }
}

// ---------------- persistence diagrams (H0 sublevel / H1 via superlevel duality) ------------
// Serial UF body byte-identical to r9-r12 (absmax 0.0). New: pending merges ballot-compacted
// into an ORDERED conflict list; the serial thread walks only conflicts (~300 total) instead
// of scanning all 2048 slots. pbd output is bit-identical.
__global__ __launch_bounds__(512) void diag_kernel(const float* __restrict__ pooled,
                                                   float* __restrict__ diag) {
    __shared__ float v_[NPIX];
    __shared__ unsigned long long keys[NPAD];
    __shared__ unsigned long long PB[NPIX];      // low 32: parent, high 32: birth (f32 bits)
    __shared__ unsigned euv[NPAD];               // u | v<<16 per edge index
    __shared__ unsigned long long pbd[NEDGE];    // low: pb bits, high: pd bits
    __shared__ unsigned long long snap[132];     // wbits<<22 | (ra+1)<<11 | (rb+1); 0 = done
    __shared__ unsigned long long clist[132];    // ordered pending merges: snap | slot<<54
    __shared__ unsigned long long smask[2];
    __shared__ unsigned claimA[NPIX];            // per-root earliest-claiming batch slot
    __shared__ unsigned histAll[2048];           // 8 wave-copies x 256 bins
    __shared__ float redA[8], redB[8];
    __shared__ float svmin, svmax;
    __shared__ unsigned long long s_prefix, s_T;
    __shared__ unsigned s_need, s_done, s_outcnt, s_ncon;

    int run = blockIdx.x;      // 0..47
    int img = run >> 1, filt = run & 1;
    int tid = threadIdx.x;
    int wv = tid >> 6;
    const float* m = pooled + img * NPIX;

    for (int i = tid; i < NPIX; i += 512) {
        float val = m[i];
        v_[i] = filt ? -val : val;
    }
    __syncthreads();
    // min/max (for the essential H0 class)
    float mn = INFINITY, mx = -INFINITY;
    for (int i = tid; i < NPIX; i += 512) { float vv = v_[i]; mn = fminf(mn, vv); mx = fmaxf(mx, vv); }
    for (int o = 32; o; o >>= 1) { mn = fminf(mn, __shfl_xor(mn, o)); mx = fmaxf(mx, __shfl_xor(mx, o)); }
    if ((tid & 63) == 0) { redA[wv] = mn; redB[wv] = mx; }
    __syncthreads();
    if (tid == 0) {
        float a = INFINITY, b = -INFINITY;
        for (int i2 = 0; i2 < 8; ++i2) { a = fminf(a, redA[i2]); b = fmaxf(b, redB[i2]); }
        svmin = a; svmax = b;
    }
    // edge keys: stable sort by (weight, edge index) — replicates jnp.argsort (stable)
    for (int e = tid; e < NPAD; e += 512) {
        unsigned long long key;
        unsigned uv = 0;
        if (e < NEDGE) {
            int u, vv;
            if (e < 992) { int r = e / 31; u = e + r; vv = u + 1; }   // horizontal
            else         { u = e - 992;   vv = u + 32; }              // vertical
            float w = fmaxf(v_[u], v_[vv]);
            unsigned int bw = __float_as_uint(w);
            bw = (bw & 0x80000000u) ? ~bw : (bw | 0x80000000u);       // orderable float bits
            key = ((unsigned long long)bw << 11) | (unsigned int)e;
            uv = (unsigned)u | ((unsigned)vv << 16);
        } else key = ~0ULL;
        keys[e] = key;
        euv[e] = uv;
    }
    for (int i = tid; i < NPIX; i += 512)
        PB[i] = ((unsigned long long)__float_as_uint(v_[i]) << 32) | (unsigned)i;
    __syncthreads();
    bitonic2048_reg(keys, tid, true);   // ascending; ends with a barrier

    // Kruskal/union-find with elder rule, batch-snapshot + parallel-commit + conflict-list.
    unsigned* PBlo = (unsigned*)PB;
    for (int base = 0; base < NEDGE; base += 128) {
        // reset claims + parallel pointer-jumping compression (roots/births untouched)
        for (int i = tid; i < NPIX; i += 512) claimA[i] = 0xFFFFFFFFu;
        if (base) {
            for (int rd = 0; rd < 4; ++rd) {
                for (int i = tid; i < NPIX; i += 512) {
                    unsigned pp = PBlo[2 * i];
                    unsigned gg = PBlo[2 * pp];
                    PBlo[2 * i] = gg;           // benign race: result is always an ancestor
                }
            }
        }
        __syncthreads();
        int bend = (base + 128 < NEDGE) ? base + 128 : NEDGE;
        int bcnt = bend - base;
        // parallel precheck: resolve snapshot roots; trivial pairs emitted; merges claim roots
        if (tid < bcnt) {
            int kk = base + tid;
            unsigned long long key = keys[kk];
            int e = (int)(key & 2047ULL);
            unsigned bw = (unsigned)(key >> 11);
            unsigned uv = euv[e];
            int ra = (int)(uv & 0xffffu), rb = (int)(uv >> 16);
            unsigned pp = PBlo[2 * ra];
            while (pp != (unsigned)ra) { ra = (int)pp; pp = PBlo[2 * ra]; }
            unsigned p2 = PBlo[2 * rb];
            while (p2 != (unsigned)rb) { rb = (int)p2; p2 = PBlo[2 * rb]; }
            if (ra == rb) {
                unsigned wb = (bw & 0x80000000u) ? (bw & 0x7fffffffu) : ~bw;
                pbd[kk] = (unsigned long long)wb | ((unsigned long long)wb << 32);
                snap[tid] = 0ULL;                                // done (trivial)
            } else {
                snap[tid] = ((unsigned long long)bw << 22)
                          | ((unsigned)(ra + 1) << 11) | (unsigned)(rb + 1);
                atomicMin(&claimA[ra], (unsigned)tid);
                atomicMin(&claimA[rb], (unsigned)tid);
            }
        }
        __syncthreads();
        // parallel commit: edges owning BOTH root claims are isolated -> exact to commit now.
        // Each slot's own thread knows its final status -> ballot-compact pending merges.
        bool pend = false;
        if (tid < bcnt) {
            unsigned long long sc = snap[tid];
            if ((unsigned)(sc & 0x3FFFFFu)) {
                int ra = (int)((sc >> 11) & 0x7FFu) - 1;
                int rb = (int)(sc & 0x7FFu) - 1;
                if (claimA[ra] == (unsigned)tid && claimA[rb] == (unsigned)tid) {
                    unsigned ob = (unsigned)(sc >> 22);
                    float w = __uint_as_float((ob & 0x80000000u) ? (ob & 0x7fffffffu) : ~ob);
                    float bu = v_[ra], bv = v_[rb];      // birth[root] == v_[root] (init-only)
                    bool uo = (bu <= bv);                // tie -> root on u's side
                    int older = uo ? ra : rb;
                    int younger = uo ? rb : ra;
                    PBlo[2 * younger] = (unsigned)older;
                    float pb_ = fmaxf(bu, bv);
                    pbd[base + tid] = (unsigned long long)__float_as_uint(pb_)
                                    | ((unsigned long long)__float_as_uint(w) << 32);
                } else pend = true;
            }
        }
        unsigned long long bmask = __ballot(pend);
        if ((tid & 63) == 0 && wv < 2) smask[wv] = bmask;
        __syncthreads();
        if (pend) {
            int lane = tid & 63;
            int pos = __popcll(bmask & ((1ULL << lane) - 1ULL))
                    + (wv ? __popcll(smask[0]) : 0);
            clist[pos] = snap[tid] | ((unsigned long long)tid << 54);
        }
        if (tid == 256) {
            unsigned n = (unsigned)(__popcll(smask[0]) + __popcll(smask[1]));
            s_ncon = n;
            clist[n] = 0ULL;         // prefetch sentinel
        }
        __syncthreads();
        // serial elder-rule scan over the ORDERED conflict list (r9-exact body)
        if (tid == 0) {
            int n = (int)s_ncon;
            unsigned long long sc = clist[0];
            for (int i = 0; i < n; ++i) {
                unsigned long long sn = clist[i + 1];            // read-only prefetch, no hazard
                int slot = (int)(sc >> 54);
                unsigned ob = (unsigned)((sc >> 22) & 0xFFFFFFFFu);
                float w = __uint_as_float((ob & 0x80000000u) ? (ob & 0x7fffffffu) : ~ob);
                int a = (int)((sc >> 11) & 0x7FFu) - 1;
                int b = (int)(sc & 0x7FFu) - 1;
                unsigned long long qa = PB[a], qb = PB[b];
                int pa = (int)(unsigned)qa, pb = (int)(unsigned)qb;
                while (pa != a || pb != b) {
                    if (pa != a) {
                        unsigned long long na = PB[pa];
                        int ga = (int)(unsigned)na;
                        PBlo[2 * a] = (unsigned)ga;     // path-halving compression
                        a = pa; pa = ga; qa = na;
                    }
                    if (pb != b) {
                        unsigned long long nb = PB[pb];
                        int gb = (int)(unsigned)nb;
                        PBlo[2 * b] = (unsigned)gb;
                        b = pb; pb = gb; qb = nb;
                    }
                }
                float pb_, pd_;
                if (a != b) {
                    float bu = __uint_as_float((unsigned)(qa >> 32));
                    float bv = __uint_as_float((unsigned)(qb >> 32));
                    bool uo = (bu <= bv);                 // tie -> root on u's side
                    int older = uo ? a : b;
                    int younger = uo ? b : a;
                    pb_ = fmaxf(bu, bv); pd_ = w;         // younger component dies
                    PBlo[2 * younger] = (unsigned)older;  // birth[older] already the min
                } else { pb_ = w; pd_ = w; }              // became trivial within batch
                pbd[base + slot] = (unsigned long long)__float_as_uint(pb_)
                                 | ((unsigned long long)__float_as_uint(pd_) << 32);
                sc = sn;
            }
        }
        __syncthreads();
    }

    // ---- top-k selection by (persistence, lower index) via radix-select ----
    // Downstream Sinkhorn is index-order-invariant, so only the selected SET matters.
    int count = filt ? NEDGE : (NEDGE + 1);
    for (int k = tid; k < NPAD; k += 512) {
        unsigned long long key = 0ULL;
        if (k < count) {
            float pers;
            if (k < NEDGE) {
                unsigned long long pd2 = pbd[k];
                pers = __uint_as_float((unsigned)(pd2 >> 32)) - __uint_as_float((unsigned)pd2);
            } else pers = svmax - svmin;
            key = ((unsigned long long)__float_as_uint(pers) << 32) | (unsigned int)(2047 - k);
        }
        keys[k] = key;
    }
    if (tid == 0) { s_prefix = 0ULL; s_T = 0ULL; s_need = KTOP; s_done = 0; s_outcnt = 0; }
    __syncthreads();

    for (int rnd = 0; rnd < 8; ++rnd) {
        for (int i = tid; i < 2048; i += 512) histAll[i] = 0;
        __syncthreads();
        if (!s_done) {
            int shift = 56 - 8 * rnd;
            unsigned long long pref = s_prefix;
            for (int k = tid; k < NPAD; k += 512) {
                unsigned long long key = keys[k];
                bool act = (rnd == 0) || ((key >> (shift + 8)) == (pref >> (shift + 8)));
                if (act) atomicAdd(&histAll[wv * 256 + (unsigned)((key >> shift) & 255ULL)], 1u);
            }
        }
        __syncthreads();
        if (wv == 0) {
            if (!s_done) {
                int l64 = tid;            // lane id within wave 0
                int shift = 56 - 8 * rnd;
                unsigned c0 = 0, c1 = 0, c2 = 0, c3 = 0;
                #pragma unroll
                for (int cp = 0; cp < 8; ++cp) {
                    const unsigned* h = histAll + cp * 256 + 4 * l64;
                    c0 += h[0]; c1 += h[1]; c2 += h[2]; c3 += h[3];
                }
                unsigned s3 = c3, s2 = c2 + s3, s1 = c1 + s2, s0 = c0 + s1;
                // wave-wide suffix sum of lane totals (s0)
                unsigned acc2 = s0;
                #pragma unroll
                for (int o = 1; o < 64; o <<= 1) {
                    unsigned v2 = __shfl_down(acc2, o);
                    if (l64 + o < 64) acc2 += v2;
                }
                unsigned above = acc2 - s0;                 // sum over lanes > l64
                unsigned Sn[5] = {above + s0, above + s1, above + s2, above + s3, above};
                unsigned need = s_need;
                #pragma unroll
                for (int q2 = 0; q2 < 4; ++q2) {
                    if (Sn[q2] >= need && Sn[q2 + 1] < need) {     // exactly one lane/bin fires
                        unsigned bstar = 4 * l64 + q2;
                        if (Sn[q2] == need) {
                            s_T = s_prefix | ((unsigned long long)bstar << shift);
                            s_done = 1;
                        } else {
                            s_prefix = s_prefix | ((unsigned long long)bstar << shift);
                            s_need = need - Sn[q2 + 1];
                        }
                    }
                }
            }
        }
        __syncthreads();
    }

    // compact selected (key >= T) and write output; order within diag is irrelevant downstream
    {
        unsigned long long T = s_T;
        for (int k = tid; k < NPAD; k += 512) {
            unsigned long long key = keys[k];
            if (key >= T && key != 0ULL) {
                int pos = (int)atomicAdd(&s_outcnt, 1u);
                int kk = 2047 - (int)(key & 0xffffffffULL);
                float b_, d_;
                if (kk < NEDGE) {
                    unsigned long long pd2 = pbd[kk];
                    b_ = __uint_as_float((unsigned)pd2);
                    d_ = __uint_as_float((unsigned)(pd2 >> 32));
                } else { b_ = svmin; d_ = svmax; }
                float ob, od;
                if (!filt) { ob = b_;  od = d_;  }       // H0 pairs
                else       { ob = -d_; od = -b_; }       // H1 = negated superlevel H0
                diag[((img * 4) + filt * 2 + 0) * KTOP + pos] = ob;
                diag[((img * 4) + filt * 2 + 1) * KTOP + pos] = od;
            }
        }
    }
}

// ---------------- entropic Sinkhorn: MFMA matvec + fold normalization ----------------------
// Byte-identical to the round-8/9/10/12 version (verified absmax 0.0).
__global__ __launch_bounds__(512) void sink_kernel(const float* __restrict__ diag,
                                                   float* __restrict__ wres) {
    __shared__ float2 sPA[KTOP], sPB[KTOP];
    __shared__ float sda[KTOP], sdb[KTOP];
    __shared__ float swa[KTOP], swb[KTOP];
    __shared__ __align__(16) unsigned ug_bf[128];    // 256 bf16
    __shared__ __align__(16) unsigned uf_bf[128];
    __shared__ __align__(16) float uf32[KTOP], ug32[KTOP];
    __shared__ __align__(16) float minF[8], accTF[8], minG[8], accTG[8];
    __shared__ __align__(16) float pm[8];
    __shared__ float s_sig, s_invsig;

    int p = blockIdx.x;            // 0..23
    int img = p % 12, dim = p / 12;
    int t = threadIdx.x;
    int lane = t & 63, w = t >> 6;         // wave 0..7
    int lr = lane & 15, lg = lane >> 4;    // col-lane, k-group
    int r = t >> 1, q = t & 1, jb = q * 128;   // mapping for maxC / final cost

    const float* ab  = diag + ((img * 4) + dim * 2) * KTOP;
    const float* ad  = ab + KTOP;
    const float* bbp = diag + (((12 + img) * 4) + dim * 2) * KTOP;
    const float* bdp = bbp + KTOP;

    if (t < KTOP) {
        float a0 = ab[t], a1 = ad[t];
        float b0 = bbp[t], b1 = bdp[t];
        sPA[t] = make_float2(a0, a1);
        sPB[t] = make_float2(b0, b1);
        sda[t] = 0.5f * (a1 - a0);
        sdb[t] = 0.5f * (b1 - b0);
    }
    if (t < 128) ug_bf[t] = 0x3F803F80u;   // u = 1.0 (bf16 pair)
    __syncthreads();

    // maxC (unscaled)
    {
        float2 A = sPA[r];
        float lmax = 0.f;
        for (int jj = 0; jj < 128; ++jj) {
            float2 B = sPB[jb + jj];
            lmax = fmaxf(lmax, fmaxf(fabsf(A.x - B.x), fabsf(A.y - B.y)));
        }
        if (t < KTOP) lmax = fmaxf(lmax, fmaxf(sda[t], sdb[t]));
        for (int o = 32; o; o >>= 1) lmax = fmaxf(lmax, __shfl_xor(lmax, o));
        if (lane == 0) pm[w] = lmax;
    }
    __syncthreads();
    if (t == 0) {
        float mc = 0.f;
        for (int i = 0; i < 8; ++i) mc = fmaxf(mc, pm[i]);
        float eps = 0.02f * fmaxf(mc, 1e-6f);
        s_sig = 1.4426950408889634f / eps;        // log2(e)/eps
        s_invsig = eps * 0.6931471805599453f;     // eps*ln2
    }
    __syncthreads();
    {
        float sig = s_sig;
        if (t < KTOP) {
            float2 a2 = sPA[t], b2 = sPB[t];
            sPA[t] = make_float2(a2.x * sig, a2.y * sig);
            sPB[t] = make_float2(b2.x * sig, b2.y * sig);
            float da2 = sda[t] * sig, db2 = sdb[t] * sig;
            sda[t] = da2; sdb[t] = db2;
            swa[t] = exp2f(-da2); swb[t] = exp2f(-db2);
        }
    }
    __syncthreads();

    // Build A-fragments: Kf (rows of K) and Kg (rows of K^T), bf16, constant across iters.
    bf16x8_t KfA0[8], KfA1[8], KgA0[8], KgA1[8];
    {
        float2 Af0 = sPA[w * 32 + lr];
        float2 Af1 = sPA[w * 32 + 16 + lr];
        float2 Bg0 = sPB[w * 32 + lr];
        float2 Bg1 = sPB[w * 32 + 16 + lr];
        #pragma unroll
        for (int ks = 0; ks < 8; ++ks) {
            #pragma unroll
            for (int jj = 0; jj < 8; ++jj) {
                int b = ks * 32 + lg * 8 + jj;
                float2 Pb = sPB[b];
                KfA0[ks][jj] = (short)bf_rne(exp2f(-fmaxf(fabsf(Af0.x - Pb.x), fabsf(Af0.y - Pb.y))));
                KfA1[ks][jj] = (short)bf_rne(exp2f(-fmaxf(fabsf(Af1.x - Pb.x), fabsf(Af1.y - Pb.y))));
                float2 Pa = sPA[b];
                KgA0[ks][jj] = (short)bf_rne(exp2f(-fmaxf(fabsf(Pa.x - Bg0.x), fabsf(Pa.y - Bg0.y))));
                KgA1[ks][jj] = (short)bf_rne(exp2f(-fmaxf(fabsf(Pa.x - Bg1.x), fabsf(Pa.y - Bg1.y))));
            }
        }
    }
    // Diagonal weights in D layout: row = w*32 + tt*16 + lg*4 + reg
    float wa0[4], wa1[4], wb0[4], wb1[4];
    #pragma unroll
    for (int g2 = 0; g2 < 4; ++g2) {
        wa0[g2] = swa[w * 32 + lg * 4 + g2];
        wa1[g2] = swa[w * 32 + 16 + lg * 4 + g2];
        wb0[g2] = swb[w * 32 + lg * 4 + g2];
        wb1[g2] = swb[w * 32 + 16 + lg * 4 + g2];
    }

    float cg = 1.f, cf = 1.f, uG2s = 1.f, uF2s = 1.f;
    f32x4_t ugs0 = {1.f, 1.f, 1.f, 1.f}, ugs1 = {1.f, 1.f, 1.f, 1.f};
    f32x4_t ufs0 = {0.f, 0.f, 0.f, 0.f}, ufs1 = {0.f, 0.f, 0.f, 0.f};

    for (int it = 0; it < NITER; ++it) {
        // ---- f phase ----
        if (it) {
            cg = min8v(minG);
            uG2s = rcpf(cf * (sum8v(accTG) + 256.f * uF2s));
        }
        {
            bf16x8_t Bf[8];
            #pragma unroll
            for (int ks = 0; ks < 8; ++ks) Bf[ks] = ((const bf16x8_t*)ug_bf)[ks * 4 + lg];
            f32x4_t a0 = {0.f, 0.f, 0.f, 0.f}, a1 = {0.f, 0.f, 0.f, 0.f};
            #pragma unroll
            for (int ks = 0; ks < 8; ++ks) {
                a0 = __builtin_amdgcn_mfma_f32_16x16x32_bf16(KfA0[ks], Bf[ks], a0, 0, 0, 0);
                a1 = __builtin_amdgcn_mfma_f32_16x16x32_bf16(KfA1[ks], Bf[ks], a1, 0, 0, 0);
            }
            float mv = INFINITY, tv = 0.f;
            #pragma unroll
            for (int g2 = 0; g2 < 4; ++g2) {
                float R0 = cg * (a0[g2] + 256.f * uG2s * wa0[g2]);
                float R1 = cg * (a1[g2] + 256.f * uG2s * wa1[g2]);
                ufs0[g2] = rcpf(R0); ufs1[g2] = rcpf(R1);
                mv = fminf(mv, fminf(R0, R1));
                tv += ugs0[g2] * wb0[g2] + ugs1[g2] * wb1[g2];   // T_f from OLD ug
            }
            if (lr == 0) {
                uint2 v0, v1;
                v0.x = bf_rne(ufs0[0]) | (bf_rne(ufs0[1]) << 16);
                v0.y = bf_rne(ufs0[2]) | (bf_rne(ufs0[3]) << 16);
                v1.x = bf_rne(ufs1[0]) | (bf_rne(ufs1[1]) << 16);
                v1.y = bf_rne(ufs1[2]) | (bf_rne(ufs1[3]) << 16);
                ((uint2*)uf_bf)[w * 8 + lg] = v0;
                ((uint2*)uf_bf)[w * 8 + 4 + lg] = v1;
            }
            wave_red2(tv, mv);
            if (lane == 0) { accTF[w] = tv * 0.0625f; minF[w] = mv; }   // rows duplicated x16
        }
        __syncthreads();
        // ---- g phase ----
        cf = min8v(minF);
        uF2s = rcpf(cg * (sum8v(accTF) + 256.f * uG2s));
        {
            bf16x8_t Bf[8];
            #pragma unroll
            for (int ks = 0; ks < 8; ++ks) Bf[ks] = ((const bf16x8_t*)uf_bf)[ks * 4 + lg];
            f32x4_t a0 = {0.f, 0.f, 0.f, 0.f}, a1 = {0.f, 0.f, 0.f, 0.f};
            #pragma unroll
            for (int ks = 0; ks < 8; ++ks) {
                a0 = __builtin_amdgcn_mfma_f32_16x16x32_bf16(KgA0[ks], Bf[ks], a0, 0, 0, 0);
                a1 = __builtin_amdgcn_mfma_f32_16x16x32_bf16(KgA1[ks], Bf[ks], a1, 0, 0, 0);
            }
            float mv = INFINITY, tv = 0.f;
            #pragma unroll
            for (int g2 = 0; g2 < 4; ++g2) {
                float Q0 = cf * (a0[g2] + 256.f * uF2s * wb0[g2]);
                float Q1 = cf * (a1[g2] + 256.f * uF2s * wb1[g2]);
                ugs0[g2] = rcpf(Q0); ugs1[g2] = rcpf(Q1);
                mv = fminf(mv, fminf(Q0, Q1));
                tv += ufs0[g2] * wa0[g2] + ufs1[g2] * wa1[g2];   // T_g from NEW uf
            }
            if (lr == 0) {
                uint2 v0, v1;
                v0.x = bf_rne(ugs0[0]) | (bf_rne(ugs0[1]) << 16);
                v0.y = bf_rne(ugs0[2]) | (bf_rne(ugs0[3]) << 16);
                v1.x = bf_rne(ugs1[0]) | (bf_rne(ugs1[1]) << 16);
                v1.y = bf_rne(ugs1[2]) | (bf_rne(ugs1[3]) << 16);
                ((uint2*)ug_bf)[w * 8 + lg] = v0;
                ((uint2*)ug_bf)[w * 8 + 4 + lg] = v1;
            }
            wave_red2(tv, mv);
            if (lane == 0) { accTG[w] = tv * 0.0625f; minG[w] = mv; }
        }
        __syncthreads();
    }
    // final G2 (after last g update); overall plan scale = cf
    float uG2f = rcpf(cf * (sum8v(accTG) + 256.f * uF2s));
    // publish exact f32 potentials for the cost epilogue
    if (lr == 0) {
        ((f32x4_t*)uf32)[w * 8 + lg] = ufs0;
        ((f32x4_t*)uf32)[w * 8 + 4 + lg] = ufs1;
        ((f32x4_t*)ug32)[w * 8 + lg] = ugs0;
        ((f32x4_t*)ug32)[w * 8 + 4 + lg] = ugs1;
    }
    __syncthreads();

    // ---- final cost sum(P*C): P_ij = cf * ufs_i * K_ij * ugs_j,  C = Mhat*invsig ----
    float accv = 0.f;
    {
        float2 Apt = sPA[r];
        float ufr = uf32[r];
        #pragma unroll 8
        for (int jj = 0; jj < 128; ++jj) {
            int j = jb + jj;
            float2 B = sPB[j];
            float Mh = fmaxf(fabsf(Apt.x - B.x), fabsf(Apt.y - B.y));
            float kv = __uint_as_float(bf_rne(exp2f(-Mh)) << 16);   // same bf16 K as iterations
            accv += ((ufr * kv) * ug32[j]) * Mh;
        }
        if (q == 0) accv += 256.f * ((ufr * swa[r]) * uG2f) * sda[r];
        else        accv += 256.f * ((uF2s * swb[r]) * ug32[r]) * sdb[r];
    }
    accv *= cf;
    for (int o = 32; o; o >>= 1) accv += __shfl_xor(accv, o);
    if (lane == 0) pm[w] = accv;
    __syncthreads();
    if (t == 0) {
        float tot = 0.f;
        for (int i = 0; i < 8; ++i) tot += pm[i];
        wres[p] = tot * s_invsig;   // back to natural units
    }
}

__global__ void finalize_kernel(const float* __restrict__ wres, float* __restrict__ out) {
    if (threadIdx.x == 0) {
        float s = 0.f;
        for (int i = 0; i < 24; ++i) s += wres[i];
        out[0] = s * 0.25f;        // / B
    }
}

extern "C" void kernel_launch(void* const* d_in, const int* in_sizes, int n_in,
                              void* d_out, int out_size, void* d_ws, size_t ws_size,
                              hipStream_t stream) {
    const float* x = (const float*)d_in[0];   // [4,4,256,256] f32
    const int* y = (const int*)d_in[1];       // [4,1,256,256] i32
    float* ws = (float*)d_ws;
    float* pooled = ws;                        // 24*1024 floats
    float* diag = pooled + 24 * NPIX;          // 24*4*256 floats
    float* wres = diag + 24 * 4 * KTOP;        // 24 floats

    pool_kernel<<<96, 256, 0, stream>>>(x, y, pooled);
    diag_kernel<<<48, 512, 0, stream>>>(pooled, diag);
    sink_kernel<<<24, 512, 0, stream>>>(diag, wres);
    finalize_kernel<<<1, 64, 0, stream>>>(wres, (float*)d_out);
}

// Round 14
// 764.564 us; speedup vs baseline: 1.0697x; 1.0042x over previous
//
#include <hip/hip_runtime.h>
#include <cmath>

#define NPIX 1024
#define NEDGE 1984
#define NPAD 2048
#define KTOP 256
#define NITER 150

typedef __attribute__((ext_vector_type(8))) short bf16x8_t;   // 8 bf16 = 4 VGPRs
typedef __attribute__((ext_vector_type(4))) float f32x4_t;

__device__ __forceinline__ unsigned bf_rne(float x) {
    unsigned b = __float_as_uint(x);
    return (b + 0x7fffu + ((b >> 16) & 1u)) >> 16;
}
__device__ __forceinline__ float rcpf(float x) { return __builtin_amdgcn_rcpf(x); }

template<int CTRL>
__device__ __forceinline__ float dppf(float x) {
    return __int_as_float(__builtin_amdgcn_update_dpp(
        __float_as_int(x), __float_as_int(x), CTRL, 0xF, 0xF, false));
}
// fused wave64 sum(s) + min(m)
__device__ __forceinline__ void wave_red2(float& s, float& m) {
    s += dppf<0x121>(s); m = fminf(m, dppf<0x121>(m));
    s += dppf<0x122>(s); m = fminf(m, dppf<0x122>(m));
    s += dppf<0x124>(s); m = fminf(m, dppf<0x124>(m));
    s += dppf<0x128>(s); m = fminf(m, dppf<0x128>(m));
    s += __int_as_float(__builtin_amdgcn_ds_swizzle(__float_as_int(s), 0x401F));
    m = fminf(m, __int_as_float(__builtin_amdgcn_ds_swizzle(__float_as_int(m), 0x401F)));
    float s0 = __int_as_float(__builtin_amdgcn_readlane(__float_as_int(s), 0));
    float s1 = __int_as_float(__builtin_amdgcn_readlane(__float_as_int(s), 32));
    s = s0 + s1;
    float m0 = __int_as_float(__builtin_amdgcn_readlane(__float_as_int(m), 0));
    float m1 = __int_as_float(__builtin_amdgcn_readlane(__float_as_int(m), 32));
    m = fminf(m0, m1);
}

__device__ __forceinline__ float min8v(const float* a) {
    float4 x0 = *(const float4*)a, x1 = *(const float4*)(a + 4);
    return fminf(fminf(fminf(x0.x, x0.y), fminf(x0.z, x0.w)),
                 fminf(fminf(x1.x, x1.y), fminf(x1.z, x1.w)));
}
__device__ __forceinline__ float sum8v(const float* a) {
    float4 x0 = *(const float4*)a, x1 = *(const float4*)(a + 4);
    return ((x0.x + x0.y) + (x0.z + x0.w)) + ((x1.x + x1.y) + (x1.z + x1.w));
}

// ---------------- pooling: softmax(x) and one-hot(y), adaptive-avg-pool 8x8 ----------------
__global__ __launch_bounds__(256) void pool_kernel(const float* __restrict__ x,
                                                   const int* __restrict__ y,
                                                   float* __restrict__ pooled) {
    int blk = blockIdx.x;              // 0..95
    int img = blk >> 2;                // 0..23
    int cell = ((blk & 3) << 8) | threadIdx.x;
    int gi = cell >> 5, gj = cell & 31;
    const float L2E = 1.4426950408889634f;
    float acc = 0.f;
    if (img < 12) {
        int b = img / 3, c = img % 3 + 1;
        const float* xb = x + (size_t)b * 262144 + (size_t)gi * 2048 + gj * 8;
        for (int pi = 0; pi < 8; ++pi) {
            const float* xr = xb + pi * 256;
            #pragma unroll
            for (int ph = 0; ph < 2; ++ph) {
                float4 c0 = *(const float4*)(xr + ph * 4);
                float4 c1 = *(const float4*)(xr + ph * 4 + 65536);
                float4 c2 = *(const float4*)(xr + ph * 4 + 131072);
                float4 c3 = *(const float4*)(xr + ph * 4 + 196608);
                const float* f0 = (const float*)&c0;
                const float* f1 = (const float*)&c1;
                const float* f2 = (const float*)&c2;
                const float* f3 = (const float*)&c3;
                #pragma unroll
                for (int k = 0; k < 4; ++k) {
                    float e0 = exp2f(f0[k] * L2E), e1 = exp2f(f1[k] * L2E);
                    float e2 = exp2f(f2[k] * L2E), e3 = exp2f(f3[k] * L2E);
                    float ec = (c == 1) ? e1 : (c == 2) ? e2 : e3;
                    acc += ec / (e0 + e1 + e2 + e3);
                }
            }
        }
    } else {
        int tt = img - 12;
        int b = tt / 3, c = tt % 3 + 1;
        const int* yb = y + (size_t)b * 65536 + (size_t)gi * 2048 + gj * 8;
        int cnt = 0;
        for (int pi = 0; pi < 8; ++pi) {
            const int* yr = yb + pi * 256;
            #pragma unroll
            for (int pj = 0; pj < 8; ++pj) cnt += (yr[pj] == c) ? 1 : 0;
        }
        acc = (float)cnt;
    }
    pooled[img * NPIX + cell] = acc * (1.f / 64.f);
}

// ---------------- bitonic sort of 2048 u64 keys, register phases for j<=2 ----------------
__device__ __forceinline__ void cex(unsigned long long& a, unsigned long long& b, bool up) {
    if ((a > b) == up) { unsigned long long t = a; a = b; b = t; }
}
__device__ void bitonic2048_reg(unsigned long long* keys, int tid, bool asc) {
    int i0 = tid << 2;   // thread owns elements i0..i0+3
    for (int k = 2; k <= NPAD; k <<= 1) {
        for (int j = k >> 1; j >= 4; j >>= 1) {
            #pragma unroll
            for (int rep = 0; rep < 4; ++rep) {
                int ii = tid + rep * 512;
                int l = ii ^ j;
                if (l > ii) {
                    unsigned long long a = keys[ii], b = keys[l];
                    bool up = (((ii & k) == 0) == asc);
                    if ((a > b) == up) { keys[ii] = b; keys[l] = a; }
                }
            }
            __syncthreads();
        }
        // j = 2 (k>=4) and j = 1 in registers; quad direction uniform for k>=4
        unsigned long long e0 = keys[i0], e1 = keys[i0 + 1], e2 = keys[i0 + 2], e3 = keys[i0 + 3];
        bool upq = (((i0 & k) == 0) == asc);
        if (k >= 4) {
            cex(e0, e2, upq); cex(e1, e3, upq);
            cex(e0, e1, upq); cex(e2, e3, upq);
        } else {   // k == 2: j=1 only, direction alternates within the quad
            cex(e0, e1, asc);
            cex(e2, e3, !asc);
        }
        keys[i0] = e0; keys[i0 + 1] = e1; keys[i0 + 2] = e2; keys[i0 + 3] = e3;
        __syncthreads();
    }
}

// ---------------- persistence diagrams (H0 sublevel / H1 via superlevel duality) ------------
// Serial UF body byte-identical to r9-r13 (absmax 0.0). New: 512-edge batches with 3 rounds
// of iterated claim-commit. Round-tagged atomicMax claims: contested roots always go to the
// LOWEST-slot claimant, so commits never jump ahead of a pending lower-slot edge sharing a
// root; isolated commits commute (r12 proof). A pending edge whose roots become equal (an
// earlier-slot commit merged the same pair) emits its diagonal pair during re-walk.
__global__ __launch_bounds__(512) void diag_kernel(const float* __restrict__ pooled,
                                                   float* __restrict__ diag) {
    __shared__ float v_[NPIX];
    __shared__ unsigned long long keys[NPAD];
    __shared__ unsigned long long PB[NPIX];      // low 32: parent, high 32: birth (f32 bits)
    __shared__ unsigned euv[NPAD];               // u | v<<16 per edge index
    __shared__ unsigned long long pbd[NEDGE];    // low: pb bits, high: pd bits
    __shared__ unsigned long long snap[516];     // wbits<<22 | (ra+1)<<11 | (rb+1); 0 = done
    __shared__ unsigned long long clist[516];    // ordered pending merges: snap | slot<<54
    __shared__ unsigned long long smask[8];
    __shared__ unsigned claimA[NPIX];            // round-tagged claims: (rnd+1)<<12 | (511-slot)
    __shared__ unsigned histAll[2048];           // 8 wave-copies x 256 bins
    __shared__ float redA[8], redB[8];
    __shared__ float svmin, svmax;
    __shared__ unsigned long long s_prefix, s_T;
    __shared__ unsigned s_need, s_done, s_outcnt, s_ncon;

    int run = blockIdx.x;      // 0..47
    int img = run >> 1, filt = run & 1;
    int tid = threadIdx.x;
    int wv = tid >> 6;
    const float* m = pooled + img * NPIX;

    for (int i = tid; i < NPIX; i += 512) {
        float val = m[i];
        v_[i] = filt ? -val : val;
    }
    __syncthreads();
    // min/max (for the essential H0 class)
    float mn = INFINITY, mx = -INFINITY;
    for (int i = tid; i < NPIX; i += 512) { float vv = v_[i]; mn = fminf(mn, vv); mx = fmaxf(mx, vv); }
    for (int o = 32; o; o >>= 1) { mn = fminf(mn, __shfl_xor(mn, o)); mx = fmaxf(mx, __shfl_xor(mx, o)); }
    if ((tid & 63) == 0) { redA[wv] = mn; redB[wv] = mx; }
    __syncthreads();
    if (tid == 0) {
        float a = INFINITY, b = -INFINITY;
        for (int i2 = 0; i2 < 8; ++i2) { a = fminf(a, redA[i2]); b = fmaxf(b, redB[i2]); }
        svmin = a; svmax = b;
    }
    // edge keys: stable sort by (weight, edge index) — replicates jnp.argsort (stable)
    for (int e = tid; e < NPAD; e += 512) {
        unsigned long long key;
        unsigned uv = 0;
        if (e < NEDGE) {
            int u, vv;
            if (e < 992) { int r = e / 31; u = e + r; vv = u + 1; }   // horizontal
            else         { u = e - 992;   vv = u + 32; }              // vertical
            float w = fmaxf(v_[u], v_[vv]);
            unsigned int bw = __float_as_uint(w);
            bw = (bw & 0x80000000u) ? ~bw : (bw | 0x80000000u);       // orderable float bits
            key = ((unsigned long long)bw << 11) | (unsigned int)e;
            uv = (unsigned)u | ((unsigned)vv << 16);
        } else key = ~0ULL;
        keys[e] = key;
        euv[e] = uv;
    }
    for (int i = tid; i < NPIX; i += 512)
        PB[i] = ((unsigned long long)__float_as_uint(v_[i]) << 32) | (unsigned)i;
    __syncthreads();
    bitonic2048_reg(keys, tid, true);   // ascending; ends with a barrier

    // Kruskal/union-find with elder rule, 512-edge batch + iterated claim-commit.
    unsigned* PBlo = (unsigned*)PB;
    for (int base = 0; base < NEDGE; base += 512) {
        // reset claims + parallel pointer-jumping compression (roots/births untouched)
        for (int i = tid; i < NPIX; i += 512) claimA[i] = 0u;
        if (base) {
            for (int rd = 0; rd < 4; ++rd) {
                for (int i = tid; i < NPIX; i += 512) {
                    unsigned pp = PBlo[2 * i];
                    unsigned gg = PBlo[2 * pp];
                    PBlo[2 * i] = gg;           // benign race: result is always an ancestor
                }
            }
        }
        __syncthreads();
        int bend = (base + 512 < NEDGE) ? base + 512 : NEDGE;
        int bcnt = bend - base;
        bool pend = false;
        // round-0 precheck: walk to snapshot roots; trivial -> emit; merge -> snap + claim
        if (tid < bcnt) {
            int kk = base + tid;
            unsigned long long key = keys[kk];
            int e = (int)(key & 2047ULL);
            unsigned bw = (unsigned)(key >> 11);
            unsigned uv = euv[e];
            int ra = (int)(uv & 0xffffu), rb = (int)(uv >> 16);
            unsigned pp = PBlo[2 * ra];
            while (pp != (unsigned)ra) { ra = (int)pp; pp = PBlo[2 * ra]; }
            unsigned p2 = PBlo[2 * rb];
            while (p2 != (unsigned)rb) { rb = (int)p2; p2 = PBlo[2 * rb]; }
            if (ra == rb) {
                unsigned wb = (bw & 0x80000000u) ? (bw & 0x7fffffffu) : ~bw;
                pbd[kk] = (unsigned long long)wb | ((unsigned long long)wb << 32);
                snap[tid] = 0ULL;                                // done (trivial)
            } else {
                snap[tid] = ((unsigned long long)bw << 22)
                          | ((unsigned)(ra + 1) << 11) | (unsigned)(rb + 1);
                unsigned tg = (1u << 12) | (unsigned)(511 - tid);
                atomicMax(&claimA[ra], tg);
                atomicMax(&claimA[rb], tg);
                pend = true;
            }
        }
        __syncthreads();
        // iterated claim-commit rounds
        for (int rnd = 0; rnd < 3; ++rnd) {
            if (pend) {
                unsigned long long sc = snap[tid];
                int ra = (int)((sc >> 11) & 0x7FFu) - 1;
                int rb = (int)(sc & 0x7FFu) - 1;
                unsigned tg = ((unsigned)(rnd + 1) << 12) | (unsigned)(511 - tid);
                if (claimA[ra] == tg && claimA[rb] == tg) {       // sole owner -> commit
                    unsigned ob = (unsigned)(sc >> 22);
                    float w = __uint_as_float((ob & 0x80000000u) ? (ob & 0x7fffffffu) : ~ob);
                    float bu = v_[ra], bv = v_[rb];   // birth[root] == v_[root] (init-only)
                    bool uo = (bu <= bv);             // tie -> root on u's side
                    int older = uo ? ra : rb;
                    int younger = uo ? rb : ra;
                    PBlo[2 * younger] = (unsigned)older;
                    float pb_ = fmaxf(bu, bv);
                    pbd[base + tid] = (unsigned long long)__float_as_uint(pb_)
                                    | ((unsigned long long)__float_as_uint(w) << 32);
                    snap[tid] = 0ULL;
                    pend = false;
                }
            }
            __syncthreads();
            if (rnd < 2) {
                if (pend) {   // re-walk to current roots (read-only), re-claim next round
                    unsigned long long sc = snap[tid];
                    int ra = (int)((sc >> 11) & 0x7FFu) - 1;
                    int rb = (int)(sc & 0x7FFu) - 1;
                    unsigned pp = PBlo[2 * ra];
                    while (pp != (unsigned)ra) { ra = (int)pp; pp = PBlo[2 * ra]; }
                    unsigned p2 = PBlo[2 * rb];
                    while (p2 != (unsigned)rb) { rb = (int)p2; p2 = PBlo[2 * rb]; }
                    if (ra == rb) {   // earlier-slot commit merged this pair -> diagonal
                        unsigned ob = (unsigned)(sc >> 22);
                        unsigned wb2 = (ob & 0x80000000u) ? (ob & 0x7fffffffu) : ~ob;
                        pbd[base + tid] = (unsigned long long)wb2
                                        | ((unsigned long long)wb2 << 32);
                        snap[tid] = 0ULL;
                        pend = false;
                    } else {
                        snap[tid] = (sc & ~0x3FFFFFULL)
                                  | ((unsigned)(ra + 1) << 11) | (unsigned)(rb + 1);
                        unsigned tg = ((unsigned)(rnd + 2) << 12) | (unsigned)(511 - tid);
                        atomicMax(&claimA[ra], tg);
                        atomicMax(&claimA[rb], tg);
                    }
                }
                __syncthreads();
            }
        }
        // ballot-compact remaining pending merges into ORDERED clist
        unsigned long long bmask = __ballot(pend);
        if ((tid & 63) == 0) smask[wv] = bmask;
        __syncthreads();
        if (pend) {
            int lane = tid & 63;
            int pos = __popcll(bmask & ((1ULL << lane) - 1ULL));
            for (int w2 = 0; w2 < wv; ++w2) pos += __popcll(smask[w2]);
            clist[pos] = snap[tid] | ((unsigned long long)tid << 54);
        }
        if (tid == 0) {
            unsigned n = 0;
            for (int w2 = 0; w2 < 8; ++w2) n += (unsigned)__popcll(smask[w2]);
            s_ncon = n;
            clist[n] = 0ULL;         // prefetch sentinel
        }
        __syncthreads();
        // serial elder-rule scan over the ORDERED conflict list (r9-exact body)
        if (tid == 0) {
            int n = (int)s_ncon;
            unsigned long long sc = clist[0];
            for (int i = 0; i < n; ++i) {
                unsigned long long sn = clist[i + 1];            // read-only prefetch, no hazard
                int slot = (int)(sc >> 54);
                unsigned ob = (unsigned)((sc >> 22) & 0xFFFFFFFFu);
                float w = __uint_as_float((ob & 0x80000000u) ? (ob & 0x7fffffffu) : ~ob);
                int a = (int)((sc >> 11) & 0x7FFu) - 1;
                int b = (int)(sc & 0x7FFu) - 1;
                unsigned long long qa = PB[a], qb = PB[b];
                int pa = (int)(unsigned)qa, pb = (int)(unsigned)qb;
                while (pa != a || pb != b) {
                    if (pa != a) {
                        unsigned long long na = PB[pa];
                        int ga = (int)(unsigned)na;
                        PBlo[2 * a] = (unsigned)ga;     // path-halving compression
                        a = pa; pa = ga; qa = na;
                    }
                    if (pb != b) {
                        unsigned long long nb = PB[pb];
                        int gb = (int)(unsigned)nb;
                        PBlo[2 * b] = (unsigned)gb;
                        b = pb; pb = gb; qb = nb;
                    }
                }
                float pb_, pd_;
                if (a != b) {
                    float bu = __uint_as_float((unsigned)(qa >> 32));
                    float bv = __uint_as_float((unsigned)(qb >> 32));
                    bool uo = (bu <= bv);                 // tie -> root on u's side
                    int older = uo ? a : b;
                    int younger = uo ? b : a;
                    pb_ = fmaxf(bu, bv); pd_ = w;         // younger component dies
                    PBlo[2 * younger] = (unsigned)older;  // birth[older] already the min
                } else { pb_ = w; pd_ = w; }              // became trivial within batch
                pbd[base + slot] = (unsigned long long)__float_as_uint(pb_)
                                 | ((unsigned long long)__float_as_uint(pd_) << 32);
                sc = sn;
            }
        }
        __syncthreads();
    }

    // ---- top-k selection by (persistence, lower index) via radix-select ----
    // Downstream Sinkhorn is index-order-invariant, so only the selected SET matters.
    int count = filt ? NEDGE : (NEDGE + 1);
    for (int k = tid; k < NPAD; k += 512) {
        unsigned long long key = 0ULL;
        if (k < count) {
            float pers;
            if (k < NEDGE) {
                unsigned long long pd2 = pbd[k];
                pers = __uint_as_float((unsigned)(pd2 >> 32)) - __uint_as_float((unsigned)pd2);
            } else pers = svmax - svmin;
            key = ((unsigned long long)__float_as_uint(pers) << 32) | (unsigned int)(2047 - k);
        }
        keys[k] = key;
    }
    if (tid == 0) { s_prefix = 0ULL; s_T = 0ULL; s_need = KTOP; s_done = 0; s_outcnt = 0; }
    __syncthreads();

    for (int rnd = 0; rnd < 8; ++rnd) {
        for (int i = tid; i < 2048; i += 512) histAll[i] = 0;
        __syncthreads();
        if (!s_done) {
            int shift = 56 - 8 * rnd;
            unsigned long long pref = s_prefix;
            for (int k = tid; k < NPAD; k += 512) {
                unsigned long long key = keys[k];
                bool act = (rnd == 0) || ((key >> (shift + 8)) == (pref >> (shift + 8)));
                if (act) atomicAdd(&histAll[wv * 256 + (unsigned)((key >> shift) & 255ULL)], 1u);
            }
        }
        __syncthreads();
        if (wv == 0) {
            if (!s_done) {
                int l64 = tid;            // lane id within wave 0
                int shift = 56 - 8 * rnd;
                unsigned c0 = 0, c1 = 0, c2 = 0, c3 = 0;
                #pragma unroll
                for (int cp = 0; cp < 8; ++cp) {
                    const unsigned* h = histAll + cp * 256 + 4 * l64;
                    c0 += h[0]; c1 += h[1]; c2 += h[2]; c3 += h[3];
                }
                unsigned s3 = c3, s2 = c2 + s3, s1 = c1 + s2, s0 = c0 + s1;
                // wave-wide suffix sum of lane totals (s0)
                unsigned acc2 = s0;
                #pragma unroll
                for (int o = 1; o < 64; o <<= 1) {
                    unsigned v2 = __shfl_down(acc2, o);
                    if (l64 + o < 64) acc2 += v2;
                }
                unsigned above = acc2 - s0;                 // sum over lanes > l64
                unsigned Sn[5] = {above + s0, above + s1, above + s2, above + s3, above};
                unsigned need = s_need;
                #pragma unroll
                for (int q2 = 0; q2 < 4; ++q2) {
                    if (Sn[q2] >= need && Sn[q2 + 1] < need) {     // exactly one lane/bin fires
                        unsigned bstar = 4 * l64 + q2;
                        if (Sn[q2] == need) {
                            s_T = s_prefix | ((unsigned long long)bstar << shift);
                            s_done = 1;
                        } else {
                            s_prefix = s_prefix | ((unsigned long long)bstar << shift);
                            s_need = need - Sn[q2 + 1];
                        }
                    }
                }
            }
        }
        __syncthreads();
    }

    // compact selected (key >= T) and write output; order within diag is irrelevant downstream
    {
        unsigned long long T = s_T;
        for (int k = tid; k < NPAD; k += 512) {
            unsigned long long key = keys[k];
            if (key >= T && key != 0ULL) {
                int pos = (int)atomicAdd(&s_outcnt, 1u);
                int kk = 2047 - (int)(key & 0xffffffffULL);
                float b_, d_;
                if (kk < NEDGE) {
                    unsigned long long pd2 = pbd[kk];
                    b_ = __uint_as_float((unsigned)pd2);
                    d_ = __uint_as_float((unsigned)(pd2 >> 32));
                } else { b_ = svmin; d_ = svmax; }
                float ob, od;
                if (!filt) { ob = b_;  od = d_;  }       // H0 pairs
                else       { ob = -d_; od = -b_; }       // H1 = negated superlevel H0
                diag[((img * 4) + filt * 2 + 0) * KTOP + pos] = ob;
                diag[((img * 4) + filt * 2 + 1) * KTOP + pos] = od;
            }
        }
    }
}

// ---------------- entropic Sinkhorn: MFMA matvec + fold normalization ----------------------
// r8-r13 structure; MFMA accumulation split into 4 independent depth-4 chains per phase
// (breaks the dependent-MFMA stall; accumulation-order change only).
__global__ __launch_bounds__(512) void sink_kernel(const float* __restrict__ diag,
                                                   float* __restrict__ wres) {
    __shared__ float2 sPA[KTOP], sPB[KTOP];
    __shared__ float sda[KTOP], sdb[KTOP];
    __shared__ float swa[KTOP], swb[KTOP];
    __shared__ __align__(16) unsigned ug_bf[128];    // 256 bf16
    __shared__ __align__(16) unsigned uf_bf[128];
    __shared__ __align__(16) float uf32[KTOP], ug32[KTOP];
    __shared__ __align__(16) float minF[8], accTF[8], minG[8], accTG[8];
    __shared__ __align__(16) float pm[8];
    __shared__ float s_sig, s_invsig;

    int p = blockIdx.x;            // 0..23
    int img = p % 12, dim = p / 12;
    int t = threadIdx.x;
    int lane = t & 63, w = t >> 6;         // wave 0..7
    int lr = lane & 15, lg = lane >> 4;    // col-lane, k-group
    int r = t >> 1, q = t & 1, jb = q * 128;   // mapping for maxC / final cost

    const float* ab  = diag + ((img * 4) + dim * 2) * KTOP;
    const float* ad  = ab + KTOP;
    const float* bbp = diag + (((12 + img) * 4) + dim * 2) * KTOP;
    const float* bdp = bbp + KTOP;

    if (t < KTOP) {
        float a0 = ab[t], a1 = ad[t];
        float b0 = bbp[t], b1 = bdp[t];
        sPA[t] = make_float2(a0, a1);
        sPB[t] = make_float2(b0, b1);
        sda[t] = 0.5f * (a1 - a0);
        sdb[t] = 0.5f * (b1 - b0);
    }
    if (t < 128) ug_bf[t] = 0x3F803F80u;   // u = 1.0 (bf16 pair)
    __syncthreads();

    // maxC (unscaled)
    {
        float2 A = sPA[r];
        float lmax = 0.f;
        for (int jj = 0; jj < 128; ++jj) {
            float2 B = sPB[jb + jj];
            lmax = fmaxf(lmax, fmaxf(fabsf(A.x - B.x), fabsf(A.y - B.y)));
        }
        if (t < KTOP) lmax = fmaxf(lmax, fmaxf(sda[t], sdb[t]));
        for (int o = 32; o; o >>= 1) lmax = fmaxf(lmax, __shfl_xor(lmax, o));
        if (lane == 0) pm[w] = lmax;
    }
    __syncthreads();
    if (t == 0) {
        float mc = 0.f;
        for (int i = 0; i < 8; ++i) mc = fmaxf(mc, pm[i]);
        float eps = 0.02f * fmaxf(mc, 1e-6f);
        s_sig = 1.4426950408889634f / eps;        // log2(e)/eps
        s_invsig = eps * 0.6931471805599453f;     // eps*ln2
    }
    __syncthreads();
    {
        float sig = s_sig;
        if (t < KTOP) {
            float2 a2 = sPA[t], b2 = sPB[t];
            sPA[t] = make_float2(a2.x * sig, a2.y * sig);
            sPB[t] = make_float2(b2.x * sig, b2.y * sig);
            float da2 = sda[t] * sig, db2 = sdb[t] * sig;
            sda[t] = da2; sdb[t] = db2;
            swa[t] = exp2f(-da2); swb[t] = exp2f(-db2);
        }
    }
    __syncthreads();

    // Build A-fragments: Kf (rows of K) and Kg (rows of K^T), bf16, constant across iters.
    bf16x8_t KfA0[8], KfA1[8], KgA0[8], KgA1[8];
    {
        float2 Af0 = sPA[w * 32 + lr];
        float2 Af1 = sPA[w * 32 + 16 + lr];
        float2 Bg0 = sPB[w * 32 + lr];
        float2 Bg1 = sPB[w * 32 + 16 + lr];
        #pragma unroll
        for (int ks = 0; ks < 8; ++ks) {
            #pragma unroll
            for (int jj = 0; jj < 8; ++jj) {
                int b = ks * 32 + lg * 8 + jj;
                float2 Pb = sPB[b];
                KfA0[ks][jj] = (short)bf_rne(exp2f(-fmaxf(fabsf(Af0.x - Pb.x), fabsf(Af0.y - Pb.y))));
                KfA1[ks][jj] = (short)bf_rne(exp2f(-fmaxf(fabsf(Af1.x - Pb.x), fabsf(Af1.y - Pb.y))));
                float2 Pa = sPA[b];
                KgA0[ks][jj] = (short)bf_rne(exp2f(-fmaxf(fabsf(Pa.x - Bg0.x), fabsf(Pa.y - Bg0.y))));
                KgA1[ks][jj] = (short)bf_rne(exp2f(-fmaxf(fabsf(Pa.x - Bg1.x), fabsf(Pa.y - Bg1.y))));
            }
        }
    }
    // Diagonal weights in D layout: row = w*32 + tt*16 + lg*4 + reg
    float wa0[4], wa1[4], wb0[4], wb1[4];
    #pragma unroll
    for (int g2 = 0; g2 < 4; ++g2) {
        wa0[g2] = swa[w * 32 + lg * 4 + g2];
        wa1[g2] = swa[w * 32 + 16 + lg * 4 + g2];
        wb0[g2] = swb[w * 32 + lg * 4 + g2];
        wb1[g2] = swb[w * 32 + 16 + lg * 4 + g2];
    }

    float cg = 1.f, cf = 1.f, uG2s = 1.f, uF2s = 1.f;
    f32x4_t ugs0 = {1.f, 1.f, 1.f, 1.f}, ugs1 = {1.f, 1.f, 1.f, 1.f};
    f32x4_t ufs0 = {0.f, 0.f, 0.f, 0.f}, ufs1 = {0.f, 0.f, 0.f, 0.f};

    for (int it = 0; it < NITER; ++it) {
        // ---- f phase ----
        if (it) {
            cg = min8v(minG);
            uG2s = rcpf(cf * (sum8v(accTG) + 256.f * uF2s));
        }
        {
            bf16x8_t Bf[8];
            #pragma unroll
            for (int ks = 0; ks < 8; ++ks) Bf[ks] = ((const bf16x8_t*)ug_bf)[ks * 4 + lg];
            f32x4_t a0 = {0.f, 0.f, 0.f, 0.f}, a1 = {0.f, 0.f, 0.f, 0.f};
            f32x4_t c0 = {0.f, 0.f, 0.f, 0.f}, c1 = {0.f, 0.f, 0.f, 0.f};
            #pragma unroll
            for (int ks = 0; ks < 4; ++ks) {
                a0 = __builtin_amdgcn_mfma_f32_16x16x32_bf16(KfA0[ks], Bf[ks], a0, 0, 0, 0);
                a1 = __builtin_amdgcn_mfma_f32_16x16x32_bf16(KfA1[ks], Bf[ks], a1, 0, 0, 0);
                c0 = __builtin_amdgcn_mfma_f32_16x16x32_bf16(KfA0[ks + 4], Bf[ks + 4], c0, 0, 0, 0);
                c1 = __builtin_amdgcn_mfma_f32_16x16x32_bf16(KfA1[ks + 4], Bf[ks + 4], c1, 0, 0, 0);
            }
            a0 = a0 + c0;
            a1 = a1 + c1;
            float mv = INFINITY, tv = 0.f;
            #pragma unroll
            for (int g2 = 0; g2 < 4; ++g2) {
                float R0 = cg * (a0[g2] + 256.f * uG2s * wa0[g2]);
                float R1 = cg * (a1[g2] + 256.f * uG2s * wa1[g2]);
                ufs0[g2] = rcpf(R0); ufs1[g2] = rcpf(R1);
                mv = fminf(mv, fminf(R0, R1));
                tv += ugs0[g2] * wb0[g2] + ugs1[g2] * wb1[g2];   // T_f from OLD ug
            }
            if (lr == 0) {
                uint2 v0, v1;
                v0.x = bf_rne(ufs0[0]) | (bf_rne(ufs0[1]) << 16);
                v0.y = bf_rne(ufs0[2]) | (bf_rne(ufs0[3]) << 16);
                v1.x = bf_rne(ufs1[0]) | (bf_rne(ufs1[1]) << 16);
                v1.y = bf_rne(ufs1[2]) | (bf_rne(ufs1[3]) << 16);
                ((uint2*)uf_bf)[w * 8 + lg] = v0;
                ((uint2*)uf_bf)[w * 8 + 4 + lg] = v1;
            }
            wave_red2(tv, mv);
            if (lane == 0) { accTF[w] = tv * 0.0625f; minF[w] = mv; }   // rows duplicated x16
        }
        __syncthreads();
        // ---- g phase ----
        cf = min8v(minF);
        uF2s = rcpf(cg * (sum8v(accTF) + 256.f * uG2s));
        {
            bf16x8_t Bf[8];
            #pragma unroll
            for (int ks = 0; ks < 8; ++ks) Bf[ks] = ((const bf16x8_t*)uf_bf)[ks * 4 + lg];
            f32x4_t a0 = {0.f, 0.f, 0.f, 0.f}, a1 = {0.f, 0.f, 0.f, 0.f};
            f32x4_t c0 = {0.f, 0.f, 0.f, 0.f}, c1 = {0.f, 0.f, 0.f, 0.f};
            #pragma unroll
            for (int ks = 0; ks < 4; ++ks) {
                a0 = __builtin_amdgcn_mfma_f32_16x16x32_bf16(KgA0[ks], Bf[ks], a0, 0, 0, 0);
                a1 = __builtin_amdgcn_mfma_f32_16x16x32_bf16(KgA1[ks], Bf[ks], a1, 0, 0, 0);
                c0 = __builtin_amdgcn_mfma_f32_16x16x32_bf16(KgA0[ks + 4], Bf[ks + 4], c0, 0, 0, 0);
                c1 = __builtin_amdgcn_mfma_f32_16x16x32_bf16(KgA1[ks + 4], Bf[ks + 4], c1, 0, 0, 0);
            }
            a0 = a0 + c0;
            a1 = a1 + c1;
            float mv = INFINITY, tv = 0.f;
            #pragma unroll
            for (int g2 = 0; g2 < 4; ++g2) {
                float Q0 = cf * (a0[g2] + 256.f * uF2s * wb0[g2]);
                float Q1 = cf * (a1[g2] + 256.f * uF2s * wb1[g2]);
                ugs0[g2] = rcpf(Q0); ugs1[g2] = rcpf(Q1);
                mv = fminf(mv, fminf(Q0, Q1));
                tv += ufs0[g2] * wa0[g2] + ufs1[g2] * wa1[g2];   // T_g from NEW uf
            }
            if (lr == 0) {
                uint2 v0, v1;
                v0.x = bf_rne(ugs0[0]) | (bf_rne(ugs0[1]) << 16);
                v0.y = bf_rne(ugs0[2]) | (bf_rne(ugs0[3]) << 16);
                v1.x = bf_rne(ugs1[0]) | (bf_rne(ugs1[1]) << 16);
                v1.y = bf_rne(ugs1[2]) | (bf_rne(ugs1[3]) << 16);
                ((uint2*)ug_bf)[w * 8 + lg] = v0;
                ((uint2*)ug_bf)[w * 8 + 4 + lg] = v1;
            }
            wave_red2(tv, mv);
            if (lane == 0) { accTG[w] = tv * 0.0625f; minG[w] = mv; }
        }
        __syncthreads();
    }
    // final G2 (after last g update); overall plan scale = cf
    float uG2f = rcpf(cf * (sum8v(accTG) + 256.f * uF2s));
    // publish exact f32 potentials for the cost epilogue
    if (lr == 0) {
        ((f32x4_t*)uf32)[w * 8 + lg] = ufs0;
        ((f32x4_t*)uf32)[w * 8 + 4 + lg] = ufs1;
        ((f32x4_t*)ug32)[w * 8 + lg] = ugs0;
        ((f32x4_t*)ug32)[w * 8 + 4 + lg] = ugs1;
    }
    __syncthreads();

    // ---- final cost sum(P*C): P_ij = cf * ufs_i * K_ij * ugs_j,  C = Mhat*invsig ----
    float accv = 0.f;
    {
        float2 Apt = sPA[r];
        float ufr = uf32[r];
        #pragma unroll 8
        for (int jj = 0; jj < 128; ++jj) {
            int j = jb + jj;
            float2 B = sPB[j];
            float Mh = fmaxf(fabsf(Apt.x - B.x), fabsf(Apt.y - B.y));
            float kv = __uint_as_float(bf_rne(exp2f(-Mh)) << 16);   // same bf16 K as iterations
            accv += ((ufr * kv) * ug32[j]) * Mh;
        }
        if (q == 0) accv += 256.f * ((ufr * swa[r]) * uG2f) * sda[r];
        else        accv += 256.f * ((uF2s * swb[r]) * ug32[r]) * sdb[r];
    }
    accv *= cf;
    for (int o = 32; o; o >>= 1) accv += __shfl_xor(accv, o);
    if (lane == 0) pm[w] = accv;
    __syncthreads();
    if (t == 0) {
        float tot = 0.f;
        for (int i = 0; i < 8; ++i) tot += pm[i];
        wres[p] = tot * s_invsig;   // back to natural units
    }
}

__global__ void finalize_kernel(const float* __restrict__ wres, float* __restrict__ out) {
    if (threadIdx.x == 0) {
        float s = 0.f;
        for (int i = 0; i < 24; ++i) s += wres[i];
        out[0] = s * 0.25f;        // / B
    }
}

extern "C" void kernel_launch(void* const* d_in, const int* in_sizes, int n_in,
                              void* d_out, int out_size, void* d_ws, size_t ws_size,
                              hipStream_t stream) {
    const float* x = (const float*)d_in[0];   // [4,4,256,256] f32
    const int* y = (const int*)d_in[1];       // [4,1,256,256] i32
    float* ws = (float*)d_ws;
    float* pooled = ws;                        // 24*1024 floats
    float* diag = pooled + 24 * NPIX;          // 24*4*256 floats
    float* wres = diag + 24 * 4 * KTOP;        // 24 floats

    pool_kernel<<<96, 256, 0, stream>>>(x, y, pooled);
    diag_kernel<<<48, 512, 0, stream>>>(pooled, diag);
    sink_kernel<<<24, 512, 0, stream>>>(diag, wres);
    finalize_kernel<<<1, 64, 0, stream>>>(wres, (float*)d_out);
}